// Round 4
// baseline (2013.959 us; speedup 1.0000x reference)
//
#include <hip/hip_runtime.h>
#include <math.h>

#define NN 50000
#define NE 1600000
#define NG 256
#define IND 128
#define HID 64
#define NREL 3
#define SLOPE 0.2f
#define XRS 192        // XR row stride in elements (3 relations * 64)
#define NRS 832        // node_rep row stride = 13*64

__device__ __forceinline__ float wred_max(float v){
  #pragma unroll
  for (int o = 32; o; o >>= 1) v = fmaxf(v, __shfl_xor(v, o));
  return v;
}
__device__ __forceinline__ float wred_sum(float v){
  #pragma unroll
  for (int o = 32; o; o >>= 1) v += __shfl_xor(v, o);
  return v;
}

__device__ __forceinline__ unsigned short f2bf(float f){
  unsigned int u = __float_as_uint(f);
  u = (u + 0x7FFFu + ((u >> 16) & 1u)) >> 16;   // RNE
  return (unsigned short)u;
}
__device__ __forceinline__ float bf2f(unsigned short h){
  return __uint_as_float(((unsigned int)h) << 16);
}

// ---- CSR build --------------------------------------------------------------

__global__ void hist_kernel(const int* __restrict__ dst, int* __restrict__ cnts){
  int e = blockIdx.x * blockDim.x + threadIdx.x;
  if (e < NE) atomicAdd(&cnts[dst[e]], 1);
}

// hierarchical exclusive scan of cnts[NN] -> rowp[NN+1]
__global__ void scan1_kernel(const int* __restrict__ cnts, int* __restrict__ rowp,
                             int* __restrict__ bsum){
  __shared__ int ws[16];
  int b = blockIdx.x, tid = threadIdx.x;
  int i = b * 1024 + tid;
  int lane = tid & 63, wid = tid >> 6;
  int v = (i < NN) ? cnts[i] : 0;
  int x = v;
  #pragma unroll
  for (int o = 1; o < 64; o <<= 1){ int t = __shfl_up(x, o); if (lane >= o) x += t; }
  if (lane == 63) ws[wid] = x;
  __syncthreads();
  if (tid < 16){
    int y = ws[tid];
    #pragma unroll
    for (int o = 1; o < 16; o <<= 1){ int t = __shfl_up(y, o); if (tid >= o) y += t; }
    ws[tid] = y;
  }
  __syncthreads();
  int off = (wid > 0) ? ws[wid - 1] : 0;
  x += off;                         // inclusive within block
  if (i < NN) rowp[i] = x - v;      // exclusive within block
  if (tid == 1023) bsum[b] = x;     // block total
}

__global__ void scan2_kernel(int* __restrict__ bsum, int* __restrict__ rowp, int nb){
  int tid = threadIdx.x;
  int v = (tid < nb) ? bsum[tid] : 0;
  int x = v;
  #pragma unroll
  for (int o = 1; o < 64; o <<= 1){ int t = __shfl_up(x, o); if (tid >= o) x += t; }
  if (tid < nb) bsum[tid] = x - v;  // exclusive block offsets
  if (tid == 63) rowp[NN] = x;      // grand total
}

__global__ void scan3_kernel(int* __restrict__ rowp, const int* __restrict__ bsum){
  int i = blockIdx.x * 1024 + threadIdx.x;
  if (i < NN) rowp[i] += bsum[blockIdx.x];
}

__global__ void scatter_kernel(const int* __restrict__ src, const int* __restrict__ dst,
                               const int* __restrict__ et, const int* __restrict__ rowp,
                               int* __restrict__ fill, int* __restrict__ csr){
  int e = blockIdx.x * blockDim.x + threadIdx.x;
  if (e >= NE) return;
  int d = dst[e];
  int pos = atomicAdd(&fill[d], 1);
  csr[rowp[d] + pos] = src[e] | (et[e] << 24);
}

// graph boundaries from sorted batch_index: gst[g] = first node with batch >= g
__global__ void gstart_kernel(const int* __restrict__ batch, int* __restrict__ gst){
  int n = blockIdx.x * blockDim.x + threadIdx.x;
  if (n > NN) return;
  int bc = (n < NN) ? batch[n] : NG;
  int bp = (n == 0) ? -1 : batch[n - 1];
  for (int g = bp + 1; g <= bc; ++g) gst[g] = n;
}

// ---- fp32 GEMM: XRb[n][r*64+h] = bf16( sum_k x[n][k] * W[r][k][h] ) ---------
// Epilogue (fp32): QK[n][r] = xr_r[n].q ; QK[n][3+r] = xr_r[n].k
__global__ __launch_bounds__(256) void mm_kernel(
    const float* __restrict__ x, int ldx, int K,
    const float* __restrict__ W, const float* __restrict__ qv, const float* __restrict__ kv,
    unsigned short* __restrict__ XRb, float* __restrict__ QK){
  __shared__ float As[16][68];   // [k][row]
  __shared__ float Bs[16][196];  // [k][col 0..191]
  int tid = threadIdx.x;
  int tx = tid & 15, ty = tid >> 4;
  int row0 = blockIdx.x * 64;
  float acc[4][12] = {};         // [row i][rel r*4 + j], col = r*64 + tx*4 + j
  int lr = tid >> 2, lc = (tid & 3) << 2;   // A: row lr, k-quad lc
  int br = tid >> 4, bc = (tid & 15) << 2;  // B: k br, col-quad bc (per relation)
  for (int k0 = 0; k0 < K; k0 += 16){
    float4 av = make_float4(0.f, 0.f, 0.f, 0.f);
    if (row0 + lr < NN) av = *(const float4*)(x + (size_t)(row0 + lr) * ldx + k0 + lc);
    As[lc + 0][lr] = av.x; As[lc + 1][lr] = av.y; As[lc + 2][lr] = av.z; As[lc + 3][lr] = av.w;
    #pragma unroll
    for (int r = 0; r < NREL; ++r)
      *(float4*)&Bs[br][r * 64 + bc] = *(const float4*)(W + ((size_t)r * K + k0 + br) * HID + bc);
    __syncthreads();
    #pragma unroll
    for (int kk = 0; kk < 16; ++kk){
      float4 a4 = *(float4*)&As[kk][ty << 2];
      float aa[4] = {a4.x, a4.y, a4.z, a4.w};
      #pragma unroll
      for (int r = 0; r < NREL; ++r){
        float4 b4 = *(float4*)&Bs[kk][r * 64 + (tx << 2)];
        float bb[4] = {b4.x, b4.y, b4.z, b4.w};
        #pragma unroll
        for (int i = 0; i < 4; ++i)
          #pragma unroll
          for (int j = 0; j < 4; ++j)
            acc[i][j + r * 4] = fmaf(aa[i], bb[j], acc[i][j + r * 4]);
      }
    }
    __syncthreads();
  }
  // store XR as bf16
  #pragma unroll
  for (int i = 0; i < 4; ++i){
    int row = row0 + (ty << 2) + i;
    if (row < NN){
      #pragma unroll
      for (int r = 0; r < NREL; ++r){
        ushort4 o4;
        o4.x = f2bf(acc[i][r * 4 + 0]);
        o4.y = f2bf(acc[i][r * 4 + 1]);
        o4.z = f2bf(acc[i][r * 4 + 2]);
        o4.w = f2bf(acc[i][r * 4 + 3]);
        *(ushort4*)(XRb + (size_t)row * XRS + r * HID + (tx << 2)) = o4;
      }
    }
  }
  // epilogue: q/k dots, reduce over tx (16 consecutive lanes) via shfl butterfly
  float q4[4], k4[4];
  #pragma unroll
  for (int j = 0; j < 4; ++j){ q4[j] = qv[(tx << 2) + j]; k4[j] = kv[(tx << 2) + j]; }
  #pragma unroll
  for (int r = 0; r < NREL; ++r){
    float pq[4], pk[4];
    #pragma unroll
    for (int i = 0; i < 4; ++i){
      float sq = 0.f, sk = 0.f;
      #pragma unroll
      for (int j = 0; j < 4; ++j){
        sq = fmaf(acc[i][r * 4 + j], q4[j], sq);
        sk = fmaf(acc[i][r * 4 + j], k4[j], sk);
      }
      pq[i] = sq; pk[i] = sk;
    }
    #pragma unroll
    for (int o = 1; o < 16; o <<= 1){
      #pragma unroll
      for (int i = 0; i < 4; ++i){
        pq[i] += __shfl_xor(pq[i], o);
        pk[i] += __shfl_xor(pk[i], o);
      }
    }
    if (tx == 0){
      #pragma unroll
      for (int i = 0; i < 4; ++i){
        int row = row0 + (ty << 2) + i;
        if (row < NN){
          QK[row * 8 + r] = pq[i];
          QK[row * 8 + 3 + r] = pk[i];
        }
      }
    }
  }
}

// ---- edge softmax + aggregation: one wave per dst node ----------------------
// Fast path (degree <= 128): logits/offsets held in registers across the
// softmax reduction — csr/QK read ONCE. Fallback path for larger degrees.

__global__ __launch_bounds__(256) void edge_kernel(
    const unsigned short* __restrict__ XRb, const float* __restrict__ QK,
    const int* __restrict__ csr, const int* __restrict__ rowp,
    const float* __restrict__ bias, float* __restrict__ out){
  int wid = blockIdx.x * 4 + (threadIdx.x >> 6);
  int lane = threadIdx.x & 63;
  if (wid >= NN) return;
  int beg = rowp[wid], end = rowp[wid + 1];
  int cnt = end - beg;
  float bv = bias[lane];
  float* op = out + (size_t)wid * NRS + lane;
  if (cnt == 0){ *op = bv; return; }
  float q0 = QK[wid * 8], q1 = QK[wid * 8 + 1], q2 = QK[wid * 8 + 2];

  if (cnt <= 128){
    float l0 = -INFINITY, l1 = -INFINITY;
    int o0 = 0, o1 = 0;
    {
      int idx = beg + lane;
      if (idx < end){
        int pk = csr[idx];
        int sn = pk & 0xFFFFFF, et = pk >> 24;
        float lg = (et == 0 ? q0 : (et == 1 ? q1 : q2)) + QK[sn * 8 + 3 + et];
        l0 = lg >= 0.f ? lg : lg * SLOPE;
        o0 = sn * XRS + et * HID;
      }
      idx += 64;
      if (idx < end){
        int pk = csr[idx];
        int sn = pk & 0xFFFFFF, et = pk >> 24;
        float lg = (et == 0 ? q0 : (et == 1 ? q1 : q2)) + QK[sn * 8 + 3 + et];
        l1 = lg >= 0.f ? lg : lg * SLOPE;
        o1 = sn * XRS + et * HID;
      }
    }
    float m = wred_max(fmaxf(l0, l1));
    float e0 = __expf(l0 - m), e1 = __expf(l1 - m);   // exp(-inf)=0 for invalid lanes
    float s = wred_sum(e0 + e1);
    float inv = 1.f / (s + 1e-16f);
    float w0 = e0 * inv, w1 = e1 * inv;
    float a0 = 0.f, a1 = 0.f, a2 = 0.f, a3 = 0.f;
    int c0 = min(64, cnt);
    #pragma unroll 4
    for (int j = 0; j < c0; ++j){
      float wj = __uint_as_float(__builtin_amdgcn_readlane(__float_as_uint(w0), j));
      int oj = __builtin_amdgcn_readlane(o0, j);
      float v = bf2f(XRb[oj + lane]);
      switch (j & 3){
        case 0: a0 = fmaf(wj, v, a0); break;
        case 1: a1 = fmaf(wj, v, a1); break;
        case 2: a2 = fmaf(wj, v, a2); break;
        default: a3 = fmaf(wj, v, a3); break;
      }
    }
    int c1 = cnt - 64;
    #pragma unroll 4
    for (int j = 0; j < c1; ++j){
      float wj = __uint_as_float(__builtin_amdgcn_readlane(__float_as_uint(w1), j));
      int oj = __builtin_amdgcn_readlane(o1, j);
      float v = bf2f(XRb[oj + lane]);
      switch (j & 3){
        case 0: a0 = fmaf(wj, v, a0); break;
        case 1: a1 = fmaf(wj, v, a1); break;
        case 2: a2 = fmaf(wj, v, a2); break;
        default: a3 = fmaf(wj, v, a3); break;
      }
    }
    *op = (a0 + a1) + (a2 + a3) + bv;
    return;
  }

  // ---- fallback: arbitrary degree, online two-pass with recompute ----
  float m = -INFINITY, s = 0.f;
  for (int c = beg; c < end; c += 64){
    int idx = c + lane;
    float l = -INFINITY;
    if (idx < end){
      int pk = csr[idx];
      int sn = pk & 0xFFFFFF, et = pk >> 24;
      float lg = (et == 0 ? q0 : (et == 1 ? q1 : q2)) + QK[sn * 8 + 3 + et];
      l = lg >= 0.f ? lg : lg * SLOPE;
    }
    float mnew = fmaxf(m, wred_max(l));
    float ps = wred_sum((idx < end) ? __expf(l - mnew) : 0.f);
    s = s * __expf(m - mnew) + ps;
    m = mnew;
  }
  float inv = 1.f / (s + 1e-16f);
  float acc = 0.f;
  for (int c = beg; c < end; c += 64){
    int idx = c + lane;
    int off = 0; float wgt = 0.f;
    if (idx < end){
      int pk = csr[idx];
      int sn = pk & 0xFFFFFF, et = pk >> 24;
      float lg = (et == 0 ? q0 : (et == 1 ? q1 : q2)) + QK[sn * 8 + 3 + et];
      float l = lg >= 0.f ? lg : lg * SLOPE;
      wgt = __expf(l - m) * inv;
      off = sn * XRS + et * HID;
    }
    int cc = min(64, end - c);
    #pragma unroll 4
    for (int j = 0; j < cc; ++j){
      float wj = __uint_as_float(__builtin_amdgcn_readlane(__float_as_uint(wgt), j));
      int oj = __builtin_amdgcn_readlane(off, j);
      acc = fmaf(wj, bf2f(XRb[oj + lane]), acc);
    }
  }
  *op = acc + bv;
}

// ---- graph-level softmax aggregation ---------------------------------------
// grid (NG, 13); block 256 = 4 node-parallel waves x 64 features

__global__ __launch_bounds__(256) void agg_kernel(
    const float* __restrict__ nr, const int* __restrict__ gst,
    const float* __restrict__ tp, float* __restrict__ out){
  __shared__ float red[4][64];
  __shared__ float red2[4][64];
  int g = blockIdx.x;
  int lane = threadIdx.x & 63;
  int w = threadIdx.x >> 6;
  int f = blockIdx.y * 64 + lane;
  int s = gst[g], e = gst[g + 1];
  float tval = tp[0];
  float m = -INFINITY;
  for (int n = s + w; n < e; n += 4)
    m = fmaxf(m, nr[(size_t)n * NRS + f] * tval);
  red[w][lane] = m;
  __syncthreads();
  m = fmaxf(fmaxf(red[0][lane], red[1][lane]), fmaxf(red[2][lane], red[3][lane]));
  float ss = 0.f, acc = 0.f;
  for (int n = s + w; n < e; n += 4){
    float v = nr[(size_t)n * NRS + f];
    float ee = __expf(v * tval - m);
    ss += ee; acc = fmaf(v, ee, acc);
  }
  __syncthreads();
  red[w][lane] = ss; red2[w][lane] = acc;
  __syncthreads();
  if (w == 0){
    ss = red[0][lane] + red[1][lane] + red[2][lane] + red[3][lane];
    acc = red2[0][lane] + red2[1][lane] + red2[2][lane] + red2[3][lane];
    out[(size_t)g * NRS + f] = acc / (ss + 1e-16f);
  }
}

// ---- orchestration ----------------------------------------------------------

extern "C" void kernel_launch(void* const* d_in, const int* in_sizes, int n_in,
                              void* d_out, int out_size, void* d_ws, size_t ws_size,
                              hipStream_t stream){
  const float* x0   = (const float*)d_in[0];
  const int*   eidx = (const int*)d_in[1];
  const int*   etyp = (const int*)d_in[2];
  const int*   batch= (const int*)d_in[3];
  const float* Wf   = (const float*)d_in[4];
  const float* qf   = (const float*)d_in[5];
  const float* kf   = (const float*)d_in[6];
  const float* bf   = (const float*)d_in[7];
  const float* Ws   = (const float*)d_in[8];
  const float* qs   = (const float*)d_in[9];
  const float* ks   = (const float*)d_in[10];
  const float* bs   = (const float*)d_in[11];
  const float* tp   = (const float*)d_in[12];

  float* gout = (float*)d_out;                 // [256][832]
  float* nrep = gout + (size_t)NG * NRS;       // [50000][832]

  char* w = (char*)d_ws;
  unsigned short* XRb = (unsigned short*)w; w += (size_t)NN * XRS * 2;  // 19.2 MB
  float* QK   = (float*)w;  w += (size_t)NN * 8 * 4;          // 1.6 MB
  int*   rowp = (int*)w;    w += (size_t)(NN + 2) * 4;
  int*   cnts = (int*)w;    w += (size_t)NN * 4;
  int*   gst  = (int*)w;    w += (size_t)(NG + 2) * 4;
  int*   bsum = (int*)w;    w += 64 * 4;
  int*   csr  = (int*)w;    w += (size_t)NE * 4;              // 6.4 MB

  const int* srcv = eidx;
  const int* dstv = eidx + NE;

  const int NB = (NN + 1023) / 1024;  // 49

  // CSR by dst + graph boundaries (once per call, reused by all 13 layers)
  hipMemsetAsync(cnts, 0, (size_t)NN * 4, stream);
  hist_kernel<<<(NE + 255) / 256, 256, 0, stream>>>(dstv, cnts);
  scan1_kernel<<<NB, 1024, 0, stream>>>(cnts, rowp, bsum);
  scan2_kernel<<<1, 64, 0, stream>>>(bsum, rowp, NB);
  scan3_kernel<<<NB, 1024, 0, stream>>>(rowp, bsum);
  hipMemsetAsync(cnts, 0, (size_t)NN * 4, stream);
  scatter_kernel<<<(NE + 255) / 256, 256, 0, stream>>>(srcv, dstv, etyp, rowp, cnts, csr);
  gstart_kernel<<<(NN + 256) / 256, 256, 0, stream>>>(batch, gst);

  for (int l = 0; l < 13; ++l){
    int K = (l == 0) ? IND : HID;
    const float* W  = (l == 0) ? Wf : (Ws + (size_t)(l - 1) * NREL * HID * HID);
    const float* q  = (l == 0) ? qf : (qs + (size_t)(l - 1) * HID);
    const float* kv = (l == 0) ? kf : (ks + (size_t)(l - 1) * HID);
    const float* b  = (l == 0) ? bf : (bs + (size_t)(l - 1) * HID);
    const float* x  = (l == 0) ? x0 : (nrep + (size_t)(l - 1) * HID);
    int ldx = (l == 0) ? IND : NRS;
    mm_kernel<<<(NN + 63) / 64, 256, 0, stream>>>(x, ldx, K, W, q, kv, XRb, QK);
    edge_kernel<<<(NN + 3) / 4, 256, 0, stream>>>(XRb, QK, csr, rowp, b, nrep + (size_t)l * HID);
  }
  dim3 ag(NG, 13);
  agg_kernel<<<ag, 256, 0, stream>>>(nrep, gst, tp, gout);
}

// Round 5
// 1217.869 us; speedup vs baseline: 1.6537x; 1.6537x over previous
//
#include <hip/hip_runtime.h>
#include <math.h>

#define NN 50000
#define NE 1600000
#define NG 256
#define IND 128
#define HID 64
#define NREL 3
#define SLOPE 0.2f
#define XRS 192        // XR row stride in elements (3 relations * 64)
#define NRS 832        // node_rep row stride = 13*64

__device__ __forceinline__ float wred_max(float v){
  #pragma unroll
  for (int o = 32; o; o >>= 1) v = fmaxf(v, __shfl_xor(v, o));
  return v;
}
__device__ __forceinline__ float wred_sum(float v){
  #pragma unroll
  for (int o = 32; o; o >>= 1) v += __shfl_xor(v, o);
  return v;
}

__device__ __forceinline__ unsigned short f2bf(float f){
  unsigned int u = __float_as_uint(f);
  u = (u + 0x7FFFu + ((u >> 16) & 1u)) >> 16;   // RNE
  return (unsigned short)u;
}
__device__ __forceinline__ float bf2f(unsigned short h){
  return __uint_as_float(((unsigned int)h) << 16);
}

// ---- CSR build --------------------------------------------------------------

__global__ void hist_kernel(const int* __restrict__ dst, int* __restrict__ cnts){
  int e = blockIdx.x * blockDim.x + threadIdx.x;
  if (e < NE) atomicAdd(&cnts[dst[e]], 1);
}

// hierarchical exclusive scan of cnts[NN] -> rowp[NN+1]
__global__ void scan1_kernel(const int* __restrict__ cnts, int* __restrict__ rowp,
                             int* __restrict__ bsum){
  __shared__ int ws[16];
  int b = blockIdx.x, tid = threadIdx.x;
  int i = b * 1024 + tid;
  int lane = tid & 63, wid = tid >> 6;
  int v = (i < NN) ? cnts[i] : 0;
  int x = v;
  #pragma unroll
  for (int o = 1; o < 64; o <<= 1){ int t = __shfl_up(x, o); if (lane >= o) x += t; }
  if (lane == 63) ws[wid] = x;
  __syncthreads();
  if (tid < 16){
    int y = ws[tid];
    #pragma unroll
    for (int o = 1; o < 16; o <<= 1){ int t = __shfl_up(y, o); if (tid >= o) y += t; }
    ws[tid] = y;
  }
  __syncthreads();
  int off = (wid > 0) ? ws[wid - 1] : 0;
  x += off;                         // inclusive within block
  if (i < NN) rowp[i] = x - v;      // exclusive within block
  if (tid == 1023) bsum[b] = x;     // block total
}

__global__ void scan2_kernel(int* __restrict__ bsum, int* __restrict__ rowp, int nb){
  int tid = threadIdx.x;
  int v = (tid < nb) ? bsum[tid] : 0;
  int x = v;
  #pragma unroll
  for (int o = 1; o < 64; o <<= 1){ int t = __shfl_up(x, o); if (tid >= o) x += t; }
  if (tid < nb) bsum[tid] = x - v;  // exclusive block offsets
  if (tid == 63) rowp[NN] = x;      // grand total
}

__global__ void scan3_kernel(int* __restrict__ rowp, const int* __restrict__ bsum){
  int i = blockIdx.x * 1024 + threadIdx.x;
  if (i < NN) rowp[i] += bsum[blockIdx.x];
}

__global__ void scatter_kernel(const int* __restrict__ src, const int* __restrict__ dst,
                               const int* __restrict__ et, const int* __restrict__ rowp,
                               int* __restrict__ fill, int* __restrict__ csr){
  int e = blockIdx.x * blockDim.x + threadIdx.x;
  if (e >= NE) return;
  int d = dst[e];
  int pos = atomicAdd(&fill[d], 1);
  csr[rowp[d] + pos] = src[e] | (et[e] << 24);
}

// graph boundaries from sorted batch_index: gst[g] = first node with batch >= g
__global__ void gstart_kernel(const int* __restrict__ batch, int* __restrict__ gst){
  int n = blockIdx.x * blockDim.x + threadIdx.x;
  if (n > NN) return;
  int bc = (n < NN) ? batch[n] : NG;
  int bp = (n == 0) ? -1 : batch[n - 1];
  for (int g = bp + 1; g <= bc; ++g) gst[g] = n;
}

// ---- fp32 GEMM: XRb[n][r*64+h] = bf16( sum_k x[n][k] * W[r][k][h] ) ---------
// Epilogue (fp32): QK[n][r] = xr_r[n].q ; QK[n][3+r] = xr_r[n].k
__global__ __launch_bounds__(256) void mm_kernel(
    const float* __restrict__ x, int ldx, int K,
    const float* __restrict__ W, const float* __restrict__ qv, const float* __restrict__ kv,
    unsigned short* __restrict__ XRb, float* __restrict__ QK){
  __shared__ float As[16][68];   // [k][row]
  __shared__ float Bs[16][196];  // [k][col 0..191]
  int tid = threadIdx.x;
  int tx = tid & 15, ty = tid >> 4;
  int row0 = blockIdx.x * 64;
  float acc[4][12] = {};         // [row i][rel r*4 + j], col = r*64 + tx*4 + j
  int lr = tid >> 2, lc = (tid & 3) << 2;   // A: row lr, k-quad lc
  int br = tid >> 4, bc = (tid & 15) << 2;  // B: k br, col-quad bc (per relation)
  for (int k0 = 0; k0 < K; k0 += 16){
    float4 av = make_float4(0.f, 0.f, 0.f, 0.f);
    if (row0 + lr < NN) av = *(const float4*)(x + (size_t)(row0 + lr) * ldx + k0 + lc);
    As[lc + 0][lr] = av.x; As[lc + 1][lr] = av.y; As[lc + 2][lr] = av.z; As[lc + 3][lr] = av.w;
    #pragma unroll
    for (int r = 0; r < NREL; ++r)
      *(float4*)&Bs[br][r * 64 + bc] = *(const float4*)(W + ((size_t)r * K + k0 + br) * HID + bc);
    __syncthreads();
    #pragma unroll
    for (int kk = 0; kk < 16; ++kk){
      float4 a4 = *(float4*)&As[kk][ty << 2];
      float aa[4] = {a4.x, a4.y, a4.z, a4.w};
      #pragma unroll
      for (int r = 0; r < NREL; ++r){
        float4 b4 = *(float4*)&Bs[kk][r * 64 + (tx << 2)];
        float bb[4] = {b4.x, b4.y, b4.z, b4.w};
        #pragma unroll
        for (int i = 0; i < 4; ++i)
          #pragma unroll
          for (int j = 0; j < 4; ++j)
            acc[i][j + r * 4] = fmaf(aa[i], bb[j], acc[i][j + r * 4]);
      }
    }
    __syncthreads();
  }
  // store XR as bf16
  #pragma unroll
  for (int i = 0; i < 4; ++i){
    int row = row0 + (ty << 2) + i;
    if (row < NN){
      #pragma unroll
      for (int r = 0; r < NREL; ++r){
        ushort4 o4;
        o4.x = f2bf(acc[i][r * 4 + 0]);
        o4.y = f2bf(acc[i][r * 4 + 1]);
        o4.z = f2bf(acc[i][r * 4 + 2]);
        o4.w = f2bf(acc[i][r * 4 + 3]);
        *(ushort4*)(XRb + (size_t)row * XRS + r * HID + (tx << 2)) = o4;
      }
    }
  }
  // epilogue: q/k dots, reduce over tx (16 consecutive lanes) via shfl butterfly
  float q4[4], k4[4];
  #pragma unroll
  for (int j = 0; j < 4; ++j){ q4[j] = qv[(tx << 2) + j]; k4[j] = kv[(tx << 2) + j]; }
  #pragma unroll
  for (int r = 0; r < NREL; ++r){
    float pq[4], pk[4];
    #pragma unroll
    for (int i = 0; i < 4; ++i){
      float sq = 0.f, sk = 0.f;
      #pragma unroll
      for (int j = 0; j < 4; ++j){
        sq = fmaf(acc[i][r * 4 + j], q4[j], sq);
        sk = fmaf(acc[i][r * 4 + j], k4[j], sk);
      }
      pq[i] = sq; pk[i] = sk;
    }
    #pragma unroll
    for (int o = 1; o < 16; o <<= 1){
      #pragma unroll
      for (int i = 0; i < 4; ++i){
        pq[i] += __shfl_xor(pq[i], o);
        pk[i] += __shfl_xor(pk[i], o);
      }
    }
    if (tx == 0){
      #pragma unroll
      for (int i = 0; i < 4; ++i){
        int row = row0 + (ty << 2) + i;
        if (row < NN){
          QK[row * 8 + r] = pq[i];
          QK[row * 8 + 3 + r] = pk[i];
        }
      }
    }
  }
}

// ---- edge softmax + aggregation: one wave per dst node ----------------------
// Fast path (degree <= 128): logits in registers; gather loop processes TWO
// edges per iteration (32-lane halves), one dword (bf16x2) load per lane.

__global__ __launch_bounds__(256) void edge_kernel(
    const unsigned short* __restrict__ XRb, const float* __restrict__ QK,
    const int* __restrict__ csr, const int* __restrict__ rowp,
    const float* __restrict__ bias, float* __restrict__ out){
  int wid = blockIdx.x * 4 + (threadIdx.x >> 6);
  int lane = threadIdx.x & 63;
  if (wid >= NN) return;
  int beg = rowp[wid], end = rowp[wid + 1];
  int cnt = end - beg;
  float* orow = out + (size_t)wid * NRS;
  int f2 = lane & 31;                       // feature-pair index (features 2*f2, 2*f2+1)
  float2 bv2 = *(const float2*)(bias + (f2 << 1));
  if (cnt == 0){
    if (lane < 32) *(float2*)(orow + (f2 << 1)) = bv2;
    return;
  }
  float q0 = QK[wid * 8], q1 = QK[wid * 8 + 1], q2 = QK[wid * 8 + 2];

  if (cnt <= 128){
    // ---- logit phase: lane = edge (up to 2 regs) ----
    float l0 = -INFINITY, l1 = -INFINITY;
    int o0 = 0, o1 = 0;
    {
      int idx = beg + lane;
      if (idx < end){
        int pk = csr[idx];
        int sn = pk & 0xFFFFFF, et = pk >> 24;
        float lg = (et == 0 ? q0 : (et == 1 ? q1 : q2)) + QK[sn * 8 + 3 + et];
        l0 = lg >= 0.f ? lg : lg * SLOPE;
        o0 = sn * XRS + et * HID;
      }
      idx += 64;
      if (idx < end){
        int pk = csr[idx];
        int sn = pk & 0xFFFFFF, et = pk >> 24;
        float lg = (et == 0 ? q0 : (et == 1 ? q1 : q2)) + QK[sn * 8 + 3 + et];
        l1 = lg >= 0.f ? lg : lg * SLOPE;
        o1 = sn * XRS + et * HID;
      }
    }
    float m = wred_max(fmaxf(l0, l1));
    float e0 = __expf(l0 - m), e1 = __expf(l1 - m);  // exp(-inf)=0 -> invalid lanes get w=0
    float s = wred_sum(e0 + e1);
    float inv = 1.f / (s + 1e-16f);
    float w0 = e0 * inv, w1 = e1 * inv;

    // ---- gather phase: halves process even/odd edges; dword = 2 bf16 feats ----
    int half = lane >> 5;
    const unsigned short* xp = XRb + (f2 << 1);
    float a0 = 0.f, a1 = 0.f, b0 = 0.f, b1 = 0.f;
    int jm0 = min(cnt, 64);
    int pA = (jm0 + 1) >> 1;                // pairs in stage A
    int p = 0;
    for (; p + 1 < pA; p += 2){
      int slA = (p << 1) + half;
      float wA = __shfl(w0, slA);
      int   oA = __shfl(o0, slA);
      int slB = slA + 2;
      float wB = __shfl(w0, slB);
      int   oB = __shfl(o0, slB);
      unsigned int dA = *(const unsigned int*)(xp + oA);
      unsigned int dB = *(const unsigned int*)(xp + oB);
      a0 = fmaf(wA, __uint_as_float(dA << 16), a0);
      a1 = fmaf(wA, __uint_as_float(dA & 0xFFFF0000u), a1);
      b0 = fmaf(wB, __uint_as_float(dB << 16), b0);
      b1 = fmaf(wB, __uint_as_float(dB & 0xFFFF0000u), b1);
    }
    if (p < pA){
      int slA = (p << 1) + half;
      float wA = __shfl(w0, slA);
      int   oA = __shfl(o0, slA);
      unsigned int dA = *(const unsigned int*)(xp + oA);
      a0 = fmaf(wA, __uint_as_float(dA << 16), a0);
      a1 = fmaf(wA, __uint_as_float(dA & 0xFFFF0000u), a1);
    }
    if (cnt > 64){
      int jm1 = cnt - 64;
      int pB = (jm1 + 1) >> 1;
      p = 0;
      for (; p + 1 < pB; p += 2){
        int slA = (p << 1) + half;
        float wA = __shfl(w1, slA);
        int   oA = __shfl(o1, slA);
        int slB = slA + 2;
        float wB = __shfl(w1, slB);
        int   oB = __shfl(o1, slB);
        unsigned int dA = *(const unsigned int*)(xp + oA);
        unsigned int dB = *(const unsigned int*)(xp + oB);
        a0 = fmaf(wA, __uint_as_float(dA << 16), a0);
        a1 = fmaf(wA, __uint_as_float(dA & 0xFFFF0000u), a1);
        b0 = fmaf(wB, __uint_as_float(dB << 16), b0);
        b1 = fmaf(wB, __uint_as_float(dB & 0xFFFF0000u), b1);
      }
      if (p < pB){
        int slA = (p << 1) + half;
        float wA = __shfl(w1, slA);
        int   oA = __shfl(o1, slA);
        unsigned int dA = *(const unsigned int*)(xp + oA);
        a0 = fmaf(wA, __uint_as_float(dA << 16), a0);
        a1 = fmaf(wA, __uint_as_float(dA & 0xFFFF0000u), a1);
      }
    }
    a0 += b0; a1 += b1;
    a0 += __shfl_xor(a0, 32);               // combine even/odd halves
    a1 += __shfl_xor(a1, 32);
    if (lane < 32){
      float2 r; r.x = a0 + bv2.x; r.y = a1 + bv2.y;
      *(float2*)(orow + (f2 << 1)) = r;
    }
    return;
  }

  // ---- fallback: arbitrary degree, online two-pass with recompute ----
  float bv = bias[lane];
  float m = -INFINITY, s = 0.f;
  for (int c = beg; c < end; c += 64){
    int idx = c + lane;
    float l = -INFINITY;
    if (idx < end){
      int pk = csr[idx];
      int sn = pk & 0xFFFFFF, et = pk >> 24;
      float lg = (et == 0 ? q0 : (et == 1 ? q1 : q2)) + QK[sn * 8 + 3 + et];
      l = lg >= 0.f ? lg : lg * SLOPE;
    }
    float mnew = fmaxf(m, wred_max(l));
    float ps = wred_sum((idx < end) ? __expf(l - mnew) : 0.f);
    s = s * __expf(m - mnew) + ps;
    m = mnew;
  }
  float inv = 1.f / (s + 1e-16f);
  float acc = 0.f;
  for (int c = beg; c < end; c += 64){
    int idx = c + lane;
    int off = 0; float wgt = 0.f;
    if (idx < end){
      int pk = csr[idx];
      int sn = pk & 0xFFFFFF, et = pk >> 24;
      float lg = (et == 0 ? q0 : (et == 1 ? q1 : q2)) + QK[sn * 8 + 3 + et];
      float l = lg >= 0.f ? lg : lg * SLOPE;
      wgt = __expf(l - m) * inv;
      off = sn * XRS + et * HID;
    }
    int cc = min(64, end - c);
    #pragma unroll 4
    for (int j = 0; j < cc; ++j){
      float wj = __uint_as_float(__builtin_amdgcn_readlane(__float_as_uint(wgt), j));
      int oj = __builtin_amdgcn_readlane(off, j);
      acc = fmaf(wj, bf2f(XRb[oj + lane]), acc);
    }
  }
  orow[lane] = acc + bv;
}

// ---- graph-level softmax aggregation ---------------------------------------
// grid (NG, 13); block 256 = 4 node-parallel waves x 64 features

__global__ __launch_bounds__(256) void agg_kernel(
    const float* __restrict__ nr, const int* __restrict__ gst,
    const float* __restrict__ tp, float* __restrict__ out){
  __shared__ float red[4][64];
  __shared__ float red2[4][64];
  int g = blockIdx.x;
  int lane = threadIdx.x & 63;
  int w = threadIdx.x >> 6;
  int f = blockIdx.y * 64 + lane;
  int s = gst[g], e = gst[g + 1];
  float tval = tp[0];
  float m = -INFINITY;
  for (int n = s + w; n < e; n += 4)
    m = fmaxf(m, nr[(size_t)n * NRS + f] * tval);
  red[w][lane] = m;
  __syncthreads();
  m = fmaxf(fmaxf(red[0][lane], red[1][lane]), fmaxf(red[2][lane], red[3][lane]));
  float ss = 0.f, acc = 0.f;
  for (int n = s + w; n < e; n += 4){
    float v = nr[(size_t)n * NRS + f];
    float ee = __expf(v * tval - m);
    ss += ee; acc = fmaf(v, ee, acc);
  }
  __syncthreads();
  red[w][lane] = ss; red2[w][lane] = acc;
  __syncthreads();
  if (w == 0){
    ss = red[0][lane] + red[1][lane] + red[2][lane] + red[3][lane];
    acc = red2[0][lane] + red2[1][lane] + red2[2][lane] + red2[3][lane];
    out[(size_t)g * NRS + f] = acc / (ss + 1e-16f);
  }
}

// ---- orchestration ----------------------------------------------------------

extern "C" void kernel_launch(void* const* d_in, const int* in_sizes, int n_in,
                              void* d_out, int out_size, void* d_ws, size_t ws_size,
                              hipStream_t stream){
  const float* x0   = (const float*)d_in[0];
  const int*   eidx = (const int*)d_in[1];
  const int*   etyp = (const int*)d_in[2];
  const int*   batch= (const int*)d_in[3];
  const float* Wf   = (const float*)d_in[4];
  const float* qf   = (const float*)d_in[5];
  const float* kf   = (const float*)d_in[6];
  const float* bf   = (const float*)d_in[7];
  const float* Ws   = (const float*)d_in[8];
  const float* qs   = (const float*)d_in[9];
  const float* ks   = (const float*)d_in[10];
  const float* bs   = (const float*)d_in[11];
  const float* tp   = (const float*)d_in[12];

  float* gout = (float*)d_out;                 // [256][832]
  float* nrep = gout + (size_t)NG * NRS;       // [50000][832]

  char* w = (char*)d_ws;
  unsigned short* XRb = (unsigned short*)w; w += (size_t)NN * XRS * 2;  // 19.2 MB
  float* QK   = (float*)w;  w += (size_t)NN * 8 * 4;          // 1.6 MB
  int*   rowp = (int*)w;    w += (size_t)(NN + 2) * 4;
  int*   cnts = (int*)w;    w += (size_t)NN * 4;
  int*   gst  = (int*)w;    w += (size_t)(NG + 2) * 4;
  int*   bsum = (int*)w;    w += 64 * 4;
  int*   csr  = (int*)w;    w += (size_t)NE * 4;              // 6.4 MB

  const int* srcv = eidx;
  const int* dstv = eidx + NE;

  const int NB = (NN + 1023) / 1024;  // 49

  // CSR by dst + graph boundaries (once per call, reused by all 13 layers)
  hipMemsetAsync(cnts, 0, (size_t)NN * 4, stream);
  hist_kernel<<<(NE + 255) / 256, 256, 0, stream>>>(dstv, cnts);
  scan1_kernel<<<NB, 1024, 0, stream>>>(cnts, rowp, bsum);
  scan2_kernel<<<1, 64, 0, stream>>>(bsum, rowp, NB);
  scan3_kernel<<<NB, 1024, 0, stream>>>(rowp, bsum);
  hipMemsetAsync(cnts, 0, (size_t)NN * 4, stream);
  scatter_kernel<<<(NE + 255) / 256, 256, 0, stream>>>(srcv, dstv, etyp, rowp, cnts, csr);
  gstart_kernel<<<(NN + 256) / 256, 256, 0, stream>>>(batch, gst);

  for (int l = 0; l < 13; ++l){
    int K = (l == 0) ? IND : HID;
    const float* W  = (l == 0) ? Wf : (Ws + (size_t)(l - 1) * NREL * HID * HID);
    const float* q  = (l == 0) ? qf : (qs + (size_t)(l - 1) * HID);
    const float* kv = (l == 0) ? kf : (ks + (size_t)(l - 1) * HID);
    const float* b  = (l == 0) ? bf : (bs + (size_t)(l - 1) * HID);
    const float* x  = (l == 0) ? x0 : (nrep + (size_t)(l - 1) * HID);
    int ldx = (l == 0) ? IND : NRS;
    mm_kernel<<<(NN + 63) / 64, 256, 0, stream>>>(x, ldx, K, W, q, kv, XRb, QK);
    edge_kernel<<<(NN + 3) / 4, 256, 0, stream>>>(XRb, QK, csr, rowp, b, nrep + (size_t)l * HID);
  }
  dim3 ag(NG, 13);
  agg_kernel<<<ag, 256, 0, stream>>>(nrep, gst, tp, gout);
}

// Round 6
// 1167.184 us; speedup vs baseline: 1.7255x; 1.0434x over previous
//
#include <hip/hip_runtime.h>
#include <math.h>

#define NN 50000
#define NE 1600000
#define NG 256
#define IND 128
#define HID 64
#define NREL 3
#define SLOPE 0.2f
#define XRS 192        // XR row stride in elements (3 relations * 64)
#define NRS 832        // node_rep row stride = 13*64

__device__ __forceinline__ float wred_max(float v){
  #pragma unroll
  for (int o = 32; o; o >>= 1) v = fmaxf(v, __shfl_xor(v, o));
  return v;
}
__device__ __forceinline__ float wred_sum(float v){
  #pragma unroll
  for (int o = 32; o; o >>= 1) v += __shfl_xor(v, o);
  return v;
}

__device__ __forceinline__ unsigned short f2bf(float f){
  unsigned int u = __float_as_uint(f);
  u = (u + 0x7FFFu + ((u >> 16) & 1u)) >> 16;   // RNE
  return (unsigned short)u;
}
__device__ __forceinline__ float bf2f(unsigned short h){
  return __uint_as_float(((unsigned int)h) << 16);
}

// ---- CSR build --------------------------------------------------------------

__global__ void hist_kernel(const int* __restrict__ dst, int* __restrict__ cnts){
  int e = blockIdx.x * blockDim.x + threadIdx.x;
  if (e < NE) atomicAdd(&cnts[dst[e]], 1);
}

// hierarchical exclusive scan of cnts[NN] -> rowp[NN+1]
__global__ void scan1_kernel(const int* __restrict__ cnts, int* __restrict__ rowp,
                             int* __restrict__ bsum){
  __shared__ int ws[16];
  int b = blockIdx.x, tid = threadIdx.x;
  int i = b * 1024 + tid;
  int lane = tid & 63, wid = tid >> 6;
  int v = (i < NN) ? cnts[i] : 0;
  int x = v;
  #pragma unroll
  for (int o = 1; o < 64; o <<= 1){ int t = __shfl_up(x, o); if (lane >= o) x += t; }
  if (lane == 63) ws[wid] = x;
  __syncthreads();
  if (tid < 16){
    int y = ws[tid];
    #pragma unroll
    for (int o = 1; o < 16; o <<= 1){ int t = __shfl_up(y, o); if (tid >= o) y += t; }
    ws[tid] = y;
  }
  __syncthreads();
  int off = (wid > 0) ? ws[wid - 1] : 0;
  x += off;                         // inclusive within block
  if (i < NN) rowp[i] = x - v;      // exclusive within block
  if (tid == 1023) bsum[b] = x;     // block total
}

__global__ void scan2_kernel(int* __restrict__ bsum, int* __restrict__ rowp, int nb){
  int tid = threadIdx.x;
  int v = (tid < nb) ? bsum[tid] : 0;
  int x = v;
  #pragma unroll
  for (int o = 1; o < 64; o <<= 1){ int t = __shfl_up(x, o); if (tid >= o) x += t; }
  if (tid < nb) bsum[tid] = x - v;  // exclusive block offsets
  if (tid == 63) rowp[NN] = x;      // grand total
}

__global__ void scan3_kernel(int* __restrict__ rowp, const int* __restrict__ bsum){
  int i = blockIdx.x * 1024 + threadIdx.x;
  if (i < NN) rowp[i] += bsum[blockIdx.x];
}

__global__ void scatter_kernel(const int* __restrict__ src, const int* __restrict__ dst,
                               const int* __restrict__ et, const int* __restrict__ rowp,
                               int* __restrict__ fill, int* __restrict__ csr){
  int e = blockIdx.x * blockDim.x + threadIdx.x;
  if (e >= NE) return;
  int d = dst[e];
  int pos = atomicAdd(&fill[d], 1);
  csr[rowp[d] + pos] = src[e] | (et[e] << 24);
}

// graph boundaries from sorted batch_index: gst[g] = first node with batch >= g
__global__ void gstart_kernel(const int* __restrict__ batch, int* __restrict__ gst){
  int n = blockIdx.x * blockDim.x + threadIdx.x;
  if (n > NN) return;
  int bc = (n < NN) ? batch[n] : NG;
  int bp = (n == 0) ? -1 : batch[n - 1];
  for (int g = bp + 1; g <= bc; ++g) gst[g] = n;
}

// ---- fp32 GEMM: XRb[n][r*64+h] = bf16( sum_k x[n][k] * W[r][k][h] ) ---------
// Epilogue (fp32): QK[n][r] = xr_r[n].q ; QK[n][3+r] = xr_r[n].k
__global__ __launch_bounds__(256) void mm_kernel(
    const float* __restrict__ x, int ldx, int K,
    const float* __restrict__ W, const float* __restrict__ qv, const float* __restrict__ kv,
    unsigned short* __restrict__ XRb, float* __restrict__ QK){
  __shared__ float As[16][68];   // [k][row]
  __shared__ float Bs[16][196];  // [k][col 0..191]
  int tid = threadIdx.x;
  int tx = tid & 15, ty = tid >> 4;
  int row0 = blockIdx.x * 64;
  float acc[4][12] = {};         // [row i][rel r*4 + j], col = r*64 + tx*4 + j
  int lr = tid >> 2, lc = (tid & 3) << 2;   // A: row lr, k-quad lc
  int br = tid >> 4, bc = (tid & 15) << 2;  // B: k br, col-quad bc (per relation)
  for (int k0 = 0; k0 < K; k0 += 16){
    float4 av = make_float4(0.f, 0.f, 0.f, 0.f);
    if (row0 + lr < NN) av = *(const float4*)(x + (size_t)(row0 + lr) * ldx + k0 + lc);
    As[lc + 0][lr] = av.x; As[lc + 1][lr] = av.y; As[lc + 2][lr] = av.z; As[lc + 3][lr] = av.w;
    #pragma unroll
    for (int r = 0; r < NREL; ++r)
      *(float4*)&Bs[br][r * 64 + bc] = *(const float4*)(W + ((size_t)r * K + k0 + br) * HID + bc);
    __syncthreads();
    #pragma unroll
    for (int kk = 0; kk < 16; ++kk){
      float4 a4 = *(float4*)&As[kk][ty << 2];
      float aa[4] = {a4.x, a4.y, a4.z, a4.w};
      #pragma unroll
      for (int r = 0; r < NREL; ++r){
        float4 b4 = *(float4*)&Bs[kk][r * 64 + (tx << 2)];
        float bb[4] = {b4.x, b4.y, b4.z, b4.w};
        #pragma unroll
        for (int i = 0; i < 4; ++i)
          #pragma unroll
          for (int j = 0; j < 4; ++j)
            acc[i][j + r * 4] = fmaf(aa[i], bb[j], acc[i][j + r * 4]);
      }
    }
    __syncthreads();
  }
  // store XR as bf16
  #pragma unroll
  for (int i = 0; i < 4; ++i){
    int row = row0 + (ty << 2) + i;
    if (row < NN){
      #pragma unroll
      for (int r = 0; r < NREL; ++r){
        ushort4 o4;
        o4.x = f2bf(acc[i][r * 4 + 0]);
        o4.y = f2bf(acc[i][r * 4 + 1]);
        o4.z = f2bf(acc[i][r * 4 + 2]);
        o4.w = f2bf(acc[i][r * 4 + 3]);
        *(ushort4*)(XRb + (size_t)row * XRS + r * HID + (tx << 2)) = o4;
      }
    }
  }
  // epilogue: q/k dots, reduce over tx (16 consecutive lanes) via shfl butterfly
  float q4[4], k4[4];
  #pragma unroll
  for (int j = 0; j < 4; ++j){ q4[j] = qv[(tx << 2) + j]; k4[j] = kv[(tx << 2) + j]; }
  #pragma unroll
  for (int r = 0; r < NREL; ++r){
    float pq[4], pk[4];
    #pragma unroll
    for (int i = 0; i < 4; ++i){
      float sq = 0.f, sk = 0.f;
      #pragma unroll
      for (int j = 0; j < 4; ++j){
        sq = fmaf(acc[i][r * 4 + j], q4[j], sq);
        sk = fmaf(acc[i][r * 4 + j], k4[j], sk);
      }
      pq[i] = sq; pk[i] = sk;
    }
    #pragma unroll
    for (int o = 1; o < 16; o <<= 1){
      #pragma unroll
      for (int i = 0; i < 4; ++i){
        pq[i] += __shfl_xor(pq[i], o);
        pk[i] += __shfl_xor(pk[i], o);
      }
    }
    if (tx == 0){
      #pragma unroll
      for (int i = 0; i < 4; ++i){
        int row = row0 + (ty << 2) + i;
        if (row < NN){
          QK[row * 8 + r] = pq[i];
          QK[row * 8 + 3 + r] = pk[i];
        }
      }
    }
  }
}

// ---- edge softmax + aggregation: one wave per dst node ----------------------
// Fast path (degree <= 128): logits in registers; gather loop processes EIGHT
// edges per iteration: 8 lanes per edge, one ushort8 (16B) load per lane.

__global__ __launch_bounds__(256) void edge_kernel(
    const unsigned short* __restrict__ XRb, const float* __restrict__ QK,
    const int* __restrict__ csr, const int* __restrict__ rowp,
    const float* __restrict__ bias, float* __restrict__ out){
  int wid = blockIdx.x * 4 + (threadIdx.x >> 6);
  int lane = threadIdx.x & 63;
  if (wid >= NN) return;
  int beg = rowp[wid], end = rowp[wid + 1];
  int cnt = end - beg;
  float* orow = out + (size_t)wid * NRS;
  int sub = lane & 7;        // feature chunk: features sub*8 .. sub*8+7
  int g   = lane >> 3;       // edge slot within group-of-8
  if (cnt == 0){
    if (lane < 8){
      float4 b0 = *(const float4*)(bias + sub * 8);
      float4 b1 = *(const float4*)(bias + sub * 8 + 4);
      *(float4*)(orow + sub * 8) = b0;
      *(float4*)(orow + sub * 8 + 4) = b1;
    }
    return;
  }
  float q0 = QK[wid * 8], q1 = QK[wid * 8 + 1], q2 = QK[wid * 8 + 2];

  if (cnt <= 128){
    // ---- logit phase: lane = edge (up to 2 regs) ----
    float l0 = -INFINITY, l1 = -INFINITY;
    int o0 = 0, o1 = 0;
    {
      int idx = beg + lane;
      if (idx < end){
        int pk = csr[idx];
        int sn = pk & 0xFFFFFF, et = pk >> 24;
        float lg = (et == 0 ? q0 : (et == 1 ? q1 : q2)) + QK[sn * 8 + 3 + et];
        l0 = lg >= 0.f ? lg : lg * SLOPE;
        o0 = sn * XRS + et * HID;
      }
      idx += 64;
      if (idx < end){
        int pk = csr[idx];
        int sn = pk & 0xFFFFFF, et = pk >> 24;
        float lg = (et == 0 ? q0 : (et == 1 ? q1 : q2)) + QK[sn * 8 + 3 + et];
        l1 = lg >= 0.f ? lg : lg * SLOPE;
        o1 = sn * XRS + et * HID;
      }
    }
    float m = wred_max(fmaxf(l0, l1));
    float e0 = __expf(l0 - m), e1 = __expf(l1 - m);  // exp(-inf)=0 -> invalid lanes get w=0
    float s = wred_sum(e0 + e1);
    float inv = 1.f / (s + 1e-16f);
    float w0 = e0 * inv, w1 = e1 * inv;

    // ---- gather phase: 8 edges/iter, 8 lanes/edge, 16B load per lane ----
    const unsigned short* xp = XRb + sub * 8;
    float acc[8] = {};
    int nA = min(cnt, 64);
    #pragma unroll 2
    for (int e = 0; e < nA; e += 8){
      int sl = e + g;
      float we = __shfl(w0, sl);         // 0 for invalid slots
      int   oe = __shfl(o0, sl);         // 0 for invalid slots (row 0, harmless)
      uint4 d = *(const uint4*)(xp + oe);
      acc[0] = fmaf(we, __uint_as_float(d.x << 16), acc[0]);
      acc[1] = fmaf(we, __uint_as_float(d.x & 0xFFFF0000u), acc[1]);
      acc[2] = fmaf(we, __uint_as_float(d.y << 16), acc[2]);
      acc[3] = fmaf(we, __uint_as_float(d.y & 0xFFFF0000u), acc[3]);
      acc[4] = fmaf(we, __uint_as_float(d.z << 16), acc[4]);
      acc[5] = fmaf(we, __uint_as_float(d.z & 0xFFFF0000u), acc[5]);
      acc[6] = fmaf(we, __uint_as_float(d.w << 16), acc[6]);
      acc[7] = fmaf(we, __uint_as_float(d.w & 0xFFFF0000u), acc[7]);
    }
    if (cnt > 64){
      int nB = cnt - 64;
      #pragma unroll 2
      for (int e = 0; e < nB; e += 8){
        int sl = e + g;
        float we = __shfl(w1, sl);
        int   oe = __shfl(o1, sl);
        uint4 d = *(const uint4*)(xp + oe);
        acc[0] = fmaf(we, __uint_as_float(d.x << 16), acc[0]);
        acc[1] = fmaf(we, __uint_as_float(d.x & 0xFFFF0000u), acc[1]);
        acc[2] = fmaf(we, __uint_as_float(d.y << 16), acc[2]);
        acc[3] = fmaf(we, __uint_as_float(d.y & 0xFFFF0000u), acc[3]);
        acc[4] = fmaf(we, __uint_as_float(d.z << 16), acc[4]);
        acc[5] = fmaf(we, __uint_as_float(d.z & 0xFFFF0000u), acc[5]);
        acc[6] = fmaf(we, __uint_as_float(d.w << 16), acc[6]);
        acc[7] = fmaf(we, __uint_as_float(d.w & 0xFFFF0000u), acc[7]);
      }
    }
    // reduce across the 8 edge-groups (lane bits 3..5)
    #pragma unroll
    for (int o = 8; o < 64; o <<= 1)
      #pragma unroll
      for (int j = 0; j < 8; ++j)
        acc[j] += __shfl_xor(acc[j], o);
    if (lane < 8){
      float4 b0 = *(const float4*)(bias + sub * 8);
      float4 b1 = *(const float4*)(bias + sub * 8 + 4);
      float4 r0, r1;
      r0.x = acc[0] + b0.x; r0.y = acc[1] + b0.y; r0.z = acc[2] + b0.z; r0.w = acc[3] + b0.w;
      r1.x = acc[4] + b1.x; r1.y = acc[5] + b1.y; r1.z = acc[6] + b1.z; r1.w = acc[7] + b1.w;
      *(float4*)(orow + sub * 8) = r0;
      *(float4*)(orow + sub * 8 + 4) = r1;
    }
    return;
  }

  // ---- fallback: arbitrary degree, online two-pass with recompute ----
  float bv = bias[lane];
  float m = -INFINITY, s = 0.f;
  for (int c = beg; c < end; c += 64){
    int idx = c + lane;
    float l = -INFINITY;
    if (idx < end){
      int pk = csr[idx];
      int sn = pk & 0xFFFFFF, et = pk >> 24;
      float lg = (et == 0 ? q0 : (et == 1 ? q1 : q2)) + QK[sn * 8 + 3 + et];
      l = lg >= 0.f ? lg : lg * SLOPE;
    }
    float mnew = fmaxf(m, wred_max(l));
    float ps = wred_sum((idx < end) ? __expf(l - mnew) : 0.f);
    s = s * __expf(m - mnew) + ps;
    m = mnew;
  }
  float inv = 1.f / (s + 1e-16f);
  float acc = 0.f;
  for (int c = beg; c < end; c += 64){
    int idx = c + lane;
    int off = 0; float wgt = 0.f;
    if (idx < end){
      int pk = csr[idx];
      int sn = pk & 0xFFFFFF, et = pk >> 24;
      float lg = (et == 0 ? q0 : (et == 1 ? q1 : q2)) + QK[sn * 8 + 3 + et];
      float l = lg >= 0.f ? lg : lg * SLOPE;
      wgt = __expf(l - m) * inv;
      off = sn * XRS + et * HID;
    }
    int cc = min(64, end - c);
    #pragma unroll 4
    for (int j = 0; j < cc; ++j){
      float wj = __uint_as_float(__builtin_amdgcn_readlane(__float_as_uint(wgt), j));
      int oj = __builtin_amdgcn_readlane(off, j);
      acc = fmaf(wj, bf2f(XRb[oj + lane]), acc);
    }
  }
  orow[lane] = acc + bv;
}

// ---- graph-level softmax aggregation ---------------------------------------
// grid (NG, 13); block 256 = 4 node-parallel waves x 64 features

__global__ __launch_bounds__(256) void agg_kernel(
    const float* __restrict__ nr, const int* __restrict__ gst,
    const float* __restrict__ tp, float* __restrict__ out){
  __shared__ float red[4][64];
  __shared__ float red2[4][64];
  int g = blockIdx.x;
  int lane = threadIdx.x & 63;
  int w = threadIdx.x >> 6;
  int f = blockIdx.y * 64 + lane;
  int s = gst[g], e = gst[g + 1];
  float tval = tp[0];
  float m = -INFINITY;
  for (int n = s + w; n < e; n += 4)
    m = fmaxf(m, nr[(size_t)n * NRS + f] * tval);
  red[w][lane] = m;
  __syncthreads();
  m = fmaxf(fmaxf(red[0][lane], red[1][lane]), fmaxf(red[2][lane], red[3][lane]));
  float ss = 0.f, acc = 0.f;
  for (int n = s + w; n < e; n += 4){
    float v = nr[(size_t)n * NRS + f];
    float ee = __expf(v * tval - m);
    ss += ee; acc = fmaf(v, ee, acc);
  }
  __syncthreads();
  red[w][lane] = ss; red2[w][lane] = acc;
  __syncthreads();
  if (w == 0){
    ss = red[0][lane] + red[1][lane] + red[2][lane] + red[3][lane];
    acc = red2[0][lane] + red2[1][lane] + red2[2][lane] + red2[3][lane];
    out[(size_t)g * NRS + f] = acc / (ss + 1e-16f);
  }
}

// ---- orchestration ----------------------------------------------------------

extern "C" void kernel_launch(void* const* d_in, const int* in_sizes, int n_in,
                              void* d_out, int out_size, void* d_ws, size_t ws_size,
                              hipStream_t stream){
  const float* x0   = (const float*)d_in[0];
  const int*   eidx = (const int*)d_in[1];
  const int*   etyp = (const int*)d_in[2];
  const int*   batch= (const int*)d_in[3];
  const float* Wf   = (const float*)d_in[4];
  const float* qf   = (const float*)d_in[5];
  const float* kf   = (const float*)d_in[6];
  const float* bf   = (const float*)d_in[7];
  const float* Ws   = (const float*)d_in[8];
  const float* qs   = (const float*)d_in[9];
  const float* ks   = (const float*)d_in[10];
  const float* bs   = (const float*)d_in[11];
  const float* tp   = (const float*)d_in[12];

  float* gout = (float*)d_out;                 // [256][832]
  float* nrep = gout + (size_t)NG * NRS;       // [50000][832]

  char* w = (char*)d_ws;
  unsigned short* XRb = (unsigned short*)w; w += (size_t)NN * XRS * 2;  // 19.2 MB
  float* QK   = (float*)w;  w += (size_t)NN * 8 * 4;          // 1.6 MB
  int*   rowp = (int*)w;    w += (size_t)(NN + 2) * 4;
  int*   cnts = (int*)w;    w += (size_t)NN * 4;
  int*   gst  = (int*)w;    w += (size_t)(NG + 2) * 4;
  int*   bsum = (int*)w;    w += 64 * 4;
  int*   csr  = (int*)w;    w += (size_t)NE * 4;              // 6.4 MB

  const int* srcv = eidx;
  const int* dstv = eidx + NE;

  const int NB = (NN + 1023) / 1024;  // 49

  // CSR by dst + graph boundaries (once per call, reused by all 13 layers)
  hipMemsetAsync(cnts, 0, (size_t)NN * 4, stream);
  hist_kernel<<<(NE + 255) / 256, 256, 0, stream>>>(dstv, cnts);
  scan1_kernel<<<NB, 1024, 0, stream>>>(cnts, rowp, bsum);
  scan2_kernel<<<1, 64, 0, stream>>>(bsum, rowp, NB);
  scan3_kernel<<<NB, 1024, 0, stream>>>(rowp, bsum);
  hipMemsetAsync(cnts, 0, (size_t)NN * 4, stream);
  scatter_kernel<<<(NE + 255) / 256, 256, 0, stream>>>(srcv, dstv, etyp, rowp, cnts, csr);
  gstart_kernel<<<(NN + 256) / 256, 256, 0, stream>>>(batch, gst);

  for (int l = 0; l < 13; ++l){
    int K = (l == 0) ? IND : HID;
    const float* W  = (l == 0) ? Wf : (Ws + (size_t)(l - 1) * NREL * HID * HID);
    const float* q  = (l == 0) ? qf : (qs + (size_t)(l - 1) * HID);
    const float* kv = (l == 0) ? kf : (ks + (size_t)(l - 1) * HID);
    const float* b  = (l == 0) ? bf : (bs + (size_t)(l - 1) * HID);
    const float* x  = (l == 0) ? x0 : (nrep + (size_t)(l - 1) * HID);
    int ldx = (l == 0) ? IND : NRS;
    mm_kernel<<<(NN + 63) / 64, 256, 0, stream>>>(x, ldx, K, W, q, kv, XRb, QK);
    edge_kernel<<<(NN + 3) / 4, 256, 0, stream>>>(XRb, QK, csr, rowp, b, nrep + (size_t)l * HID);
  }
  dim3 ag(NG, 13);
  agg_kernel<<<ag, 256, 0, stream>>>(nrep, gst, tp, gout);
}

// Round 7
// 1053.450 us; speedup vs baseline: 1.9118x; 1.1080x over previous
//
#include <hip/hip_runtime.h>
#include <math.h>

#define NN 50000
#define NE 1600000
#define NG 256
#define IND 128
#define HID 64
#define NREL 3
#define SLOPE 0.2f
#define XRS 192        // XR row stride in elements (3 relations * 64)
#define NRS 832        // node_rep row stride = 13*64
#define WTP 136        // padded LDS stride for Wt (shorts): mult of 8 -> 16B aligned

typedef short bf16x8 __attribute__((ext_vector_type(8)));
typedef float f32x4 __attribute__((ext_vector_type(4)));

__device__ __forceinline__ float wred_max(float v){
  #pragma unroll
  for (int o = 32; o; o >>= 1) v = fmaxf(v, __shfl_xor(v, o));
  return v;
}
__device__ __forceinline__ float wred_sum(float v){
  #pragma unroll
  for (int o = 32; o; o >>= 1) v += __shfl_xor(v, o);
  return v;
}

__device__ __forceinline__ unsigned short f2bf(float f){
  unsigned int u = __float_as_uint(f);
  u = (u + 0x7FFFu + ((u >> 16) & 1u)) >> 16;   // RNE
  return (unsigned short)u;
}
__device__ __forceinline__ float bf2f(unsigned short h){
  return __uint_as_float(((unsigned int)h) << 16);
}

// ---- CSR build --------------------------------------------------------------

__global__ void hist_kernel(const int* __restrict__ dst, int* __restrict__ cnts){
  int e = blockIdx.x * blockDim.x + threadIdx.x;
  if (e < NE) atomicAdd(&cnts[dst[e]], 1);
}

// hierarchical exclusive scan of cnts[NN] -> rowp[NN+1]
__global__ void scan1_kernel(const int* __restrict__ cnts, int* __restrict__ rowp,
                             int* __restrict__ bsum){
  __shared__ int ws[16];
  int b = blockIdx.x, tid = threadIdx.x;
  int i = b * 1024 + tid;
  int lane = tid & 63, wid = tid >> 6;
  int v = (i < NN) ? cnts[i] : 0;
  int x = v;
  #pragma unroll
  for (int o = 1; o < 64; o <<= 1){ int t = __shfl_up(x, o); if (lane >= o) x += t; }
  if (lane == 63) ws[wid] = x;
  __syncthreads();
  if (tid < 16){
    int y = ws[tid];
    #pragma unroll
    for (int o = 1; o < 16; o <<= 1){ int t = __shfl_up(y, o); if (tid >= o) y += t; }
    ws[tid] = y;
  }
  __syncthreads();
  int off = (wid > 0) ? ws[wid - 1] : 0;
  x += off;                         // inclusive within block
  if (i < NN) rowp[i] = x - v;      // exclusive within block
  if (tid == 1023) bsum[b] = x;     // block total
}

__global__ void scan2_kernel(int* __restrict__ bsum, int* __restrict__ rowp, int nb){
  int tid = threadIdx.x;
  int v = (tid < nb) ? bsum[tid] : 0;
  int x = v;
  #pragma unroll
  for (int o = 1; o < 64; o <<= 1){ int t = __shfl_up(x, o); if (tid >= o) x += t; }
  if (tid < nb) bsum[tid] = x - v;  // exclusive block offsets
  if (tid == 63) rowp[NN] = x;      // grand total
}

__global__ void scan3_kernel(int* __restrict__ rowp, const int* __restrict__ bsum){
  int i = blockIdx.x * 1024 + threadIdx.x;
  if (i < NN) rowp[i] += bsum[blockIdx.x];
}

__global__ void scatter_kernel(const int* __restrict__ src, const int* __restrict__ dst,
                               const int* __restrict__ et, const int* __restrict__ rowp,
                               int* __restrict__ fill, int* __restrict__ csr){
  int e = blockIdx.x * blockDim.x + threadIdx.x;
  if (e >= NE) return;
  int d = dst[e];
  int pos = atomicAdd(&fill[d], 1);
  csr[rowp[d] + pos] = src[e] | (et[e] << 24);
}

// graph boundaries from sorted batch_index: gst[g] = first node with batch >= g
__global__ void gstart_kernel(const int* __restrict__ batch, int* __restrict__ gst){
  int n = blockIdx.x * blockDim.x + threadIdx.x;
  if (n > NN) return;
  int bc = (n < NN) ? batch[n] : NG;
  int bp = (n == 0) ? -1 : batch[n - 1];
  for (int g = bp + 1; g <= bc; ++g) gst[g] = n;
}

// ---- weight prep: Wtg[col=r*64+h][k] = bf16(W[r][k][h]) ---------------------
__global__ void wprep_kernel(const float* __restrict__ W, unsigned short* __restrict__ Wtg, int K){
  int i = blockIdx.x * blockDim.x + threadIdx.x;
  if (i >= NREL * K * HID) return;
  int h = i & 63;
  int k = (i >> 6) % K;
  int r = i / (K * HID);
  Wtg[(size_t)((r << 6) + h) * K + k] = f2bf(W[i]);
}

// ---- MFMA GEMM: XRb[n][f] = bf16( sum_k x[n][k] * W[f][k] ), f = r*64+h ----
// A-op = W (M=16 features x K), B-op = x (K x N=16 rows).
// D layout: lane&15 = x-row, (lane>>4)*4+reg = feature  -> packed ushort4 C-store.
// Epilogue: QK[n][r] = xr_r . q ; QK[n][3+r] = xr_r . k  (xor-16/32 reduce)
__global__ __launch_bounds__(256) void mm_kernel(
    const float* __restrict__ x, int ldx, int K,
    const unsigned short* __restrict__ Wtg,
    const float* __restrict__ qv, const float* __restrict__ kv,
    unsigned short* __restrict__ XRb, float* __restrict__ QK){
  __shared__ unsigned short Wt[192 * WTP];
  int tid = threadIdx.x;
  int w = tid >> 6, lane = tid & 63;
  int lrow = lane & 15, kg = lane >> 4;      // x-row within wave tile, k-group
  int row0 = blockIdx.x * 64;
  int row = row0 + w * 16 + lrow;
  // stage Wtg -> LDS (16B copies, coalesced / conflict-free)
  int nb8 = 192 * (K >> 3);
  for (int i = tid; i < nb8; i += 256){
    int col = i / (K >> 3);
    int k8 = (i - col * (K >> 3)) << 3;
    *(bf16x8*)&Wt[col * WTP + k8] = *(const bf16x8*)&Wtg[(size_t)col * K + k8];
  }
  __syncthreads();

  f32x4 acc[12];
  #pragma unroll
  for (int t = 0; t < 12; ++t) acc[t] = (f32x4){0.f, 0.f, 0.f, 0.f};

  int ksteps = K >> 5;
  for (int ks = 0; ks < ksteps; ++ks){
    // x-fragment (B-op): 8 consecutive k as bf16
    bf16x8 xb;
    if (row < NN){
      const float* xp = x + (size_t)row * ldx + (ks << 5) + (kg << 3);
      float4 v0 = *(const float4*)xp;
      float4 v1 = *(const float4*)(xp + 4);
      xb[0] = (short)f2bf(v0.x); xb[1] = (short)f2bf(v0.y);
      xb[2] = (short)f2bf(v0.z); xb[3] = (short)f2bf(v0.w);
      xb[4] = (short)f2bf(v1.x); xb[5] = (short)f2bf(v1.y);
      xb[6] = (short)f2bf(v1.z); xb[7] = (short)f2bf(v1.w);
    } else {
      #pragma unroll
      for (int j = 0; j < 8; ++j) xb[j] = 0;
    }
    int kk = (ks << 5) + (kg << 3);
    #pragma unroll
    for (int t = 0; t < 12; ++t){
      bf16x8 wf = *(const bf16x8*)&Wt[(t * 16 + lrow) * WTP + kk];
      acc[t] = __builtin_amdgcn_mfma_f32_16x16x32_bf16(wf, xb, acc[t], 0, 0, 0);
    }
  }

  // C-store: lane holds features t*16 + kg*4 + j for x-row `row`
  if (row < NN){
    unsigned short* orow = XRb + (size_t)row * XRS;
    #pragma unroll
    for (int t = 0; t < 12; ++t){
      ushort4 o4;
      o4.x = f2bf(acc[t][0]); o4.y = f2bf(acc[t][1]);
      o4.z = f2bf(acc[t][2]); o4.w = f2bf(acc[t][3]);
      *(ushort4*)(orow + t * 16 + (kg << 2)) = o4;
    }
  }

  // epilogue: q/k dots. feature of (t,j) within relation: hcol = (t&3)*16 + kg*4 + j
  float pq[3] = {0,0,0}, pk[3] = {0,0,0};
  #pragma unroll
  for (int t = 0; t < 12; ++t){
    int r = t >> 2;
    int hbase = ((t & 3) << 4) + (kg << 2);
    #pragma unroll
    for (int j = 0; j < 4; ++j){
      float qc = qv[hbase + j], kc = kv[hbase + j];
      pq[r] = fmaf(acc[t][j], qc, pq[r]);
      pk[r] = fmaf(acc[t][j], kc, pk[r]);
    }
  }
  #pragma unroll
  for (int o = 16; o < 64; o <<= 1){
    #pragma unroll
    for (int r = 0; r < 3; ++r){
      pq[r] += __shfl_xor(pq[r], o);
      pk[r] += __shfl_xor(pk[r], o);
    }
  }
  if (kg == 0 && row < NN){
    #pragma unroll
    for (int r = 0; r < 3; ++r){
      QK[row * 8 + r] = pq[r];
      QK[row * 8 + 3 + r] = pk[r];
    }
  }
}

// ---- edge softmax + aggregation: one wave per dst node ----------------------
// Fast path (degree <= 128): logits in registers; gather loop processes EIGHT
// edges per iteration: 8 lanes per edge, one ushort8 (16B) load per lane.

__global__ __launch_bounds__(256) void edge_kernel(
    const unsigned short* __restrict__ XRb, const float* __restrict__ QK,
    const int* __restrict__ csr, const int* __restrict__ rowp,
    const float* __restrict__ bias, float* __restrict__ out){
  int wid = blockIdx.x * 4 + (threadIdx.x >> 6);
  int lane = threadIdx.x & 63;
  if (wid >= NN) return;
  int beg = rowp[wid], end = rowp[wid + 1];
  int cnt = end - beg;
  float* orow = out + (size_t)wid * NRS;
  int sub = lane & 7;        // feature chunk: features sub*8 .. sub*8+7
  int g   = lane >> 3;       // edge slot within group-of-8
  if (cnt == 0){
    if (lane < 8){
      float4 b0 = *(const float4*)(bias + sub * 8);
      float4 b1 = *(const float4*)(bias + sub * 8 + 4);
      *(float4*)(orow + sub * 8) = b0;
      *(float4*)(orow + sub * 8 + 4) = b1;
    }
    return;
  }
  float q0 = QK[wid * 8], q1 = QK[wid * 8 + 1], q2 = QK[wid * 8 + 2];

  if (cnt <= 128){
    // ---- logit phase: lane = edge (up to 2 regs) ----
    float l0 = -INFINITY, l1 = -INFINITY;
    int o0 = 0, o1 = 0;
    {
      int idx = beg + lane;
      if (idx < end){
        int pk = csr[idx];
        int sn = pk & 0xFFFFFF, et = pk >> 24;
        float lg = (et == 0 ? q0 : (et == 1 ? q1 : q2)) + QK[sn * 8 + 3 + et];
        l0 = lg >= 0.f ? lg : lg * SLOPE;
        o0 = sn * XRS + et * HID;
      }
      idx += 64;
      if (idx < end){
        int pk = csr[idx];
        int sn = pk & 0xFFFFFF, et = pk >> 24;
        float lg = (et == 0 ? q0 : (et == 1 ? q1 : q2)) + QK[sn * 8 + 3 + et];
        l1 = lg >= 0.f ? lg : lg * SLOPE;
        o1 = sn * XRS + et * HID;
      }
    }
    float m = wred_max(fmaxf(l0, l1));
    float e0 = __expf(l0 - m), e1 = __expf(l1 - m);  // exp(-inf)=0 -> invalid lanes get w=0
    float s = wred_sum(e0 + e1);
    float inv = 1.f / (s + 1e-16f);
    float w0 = e0 * inv, w1 = e1 * inv;

    // ---- gather phase: 8 edges/iter, 8 lanes/edge, 16B load per lane ----
    const unsigned short* xp = XRb + sub * 8;
    float acc[8] = {};
    int nA = min(cnt, 64);
    #pragma unroll 2
    for (int e = 0; e < nA; e += 8){
      int sl = e + g;
      float we = __shfl(w0, sl);         // 0 for invalid slots
      int   oe = __shfl(o0, sl);         // 0 for invalid slots (row 0, harmless)
      uint4 d = *(const uint4*)(xp + oe);
      acc[0] = fmaf(we, __uint_as_float(d.x << 16), acc[0]);
      acc[1] = fmaf(we, __uint_as_float(d.x & 0xFFFF0000u), acc[1]);
      acc[2] = fmaf(we, __uint_as_float(d.y << 16), acc[2]);
      acc[3] = fmaf(we, __uint_as_float(d.y & 0xFFFF0000u), acc[3]);
      acc[4] = fmaf(we, __uint_as_float(d.z << 16), acc[4]);
      acc[5] = fmaf(we, __uint_as_float(d.z & 0xFFFF0000u), acc[5]);
      acc[6] = fmaf(we, __uint_as_float(d.w << 16), acc[6]);
      acc[7] = fmaf(we, __uint_as_float(d.w & 0xFFFF0000u), acc[7]);
    }
    if (cnt > 64){
      int nB = cnt - 64;
      #pragma unroll 2
      for (int e = 0; e < nB; e += 8){
        int sl = e + g;
        float we = __shfl(w1, sl);
        int   oe = __shfl(o1, sl);
        uint4 d = *(const uint4*)(xp + oe);
        acc[0] = fmaf(we, __uint_as_float(d.x << 16), acc[0]);
        acc[1] = fmaf(we, __uint_as_float(d.x & 0xFFFF0000u), acc[1]);
        acc[2] = fmaf(we, __uint_as_float(d.y << 16), acc[2]);
        acc[3] = fmaf(we, __uint_as_float(d.y & 0xFFFF0000u), acc[3]);
        acc[4] = fmaf(we, __uint_as_float(d.z << 16), acc[4]);
        acc[5] = fmaf(we, __uint_as_float(d.z & 0xFFFF0000u), acc[5]);
        acc[6] = fmaf(we, __uint_as_float(d.w << 16), acc[6]);
        acc[7] = fmaf(we, __uint_as_float(d.w & 0xFFFF0000u), acc[7]);
      }
    }
    // reduce across the 8 edge-groups (lane bits 3..5)
    #pragma unroll
    for (int o = 8; o < 64; o <<= 1)
      #pragma unroll
      for (int j = 0; j < 8; ++j)
        acc[j] += __shfl_xor(acc[j], o);
    if (lane < 8){
      float4 b0 = *(const float4*)(bias + sub * 8);
      float4 b1 = *(const float4*)(bias + sub * 8 + 4);
      float4 r0, r1;
      r0.x = acc[0] + b0.x; r0.y = acc[1] + b0.y; r0.z = acc[2] + b0.z; r0.w = acc[3] + b0.w;
      r1.x = acc[4] + b1.x; r1.y = acc[5] + b1.y; r1.z = acc[6] + b1.z; r1.w = acc[7] + b1.w;
      *(float4*)(orow + sub * 8) = r0;
      *(float4*)(orow + sub * 8 + 4) = r1;
    }
    return;
  }

  // ---- fallback: arbitrary degree, online two-pass with recompute ----
  float bv = bias[lane];
  float m = -INFINITY, s = 0.f;
  for (int c = beg; c < end; c += 64){
    int idx = c + lane;
    float l = -INFINITY;
    if (idx < end){
      int pk = csr[idx];
      int sn = pk & 0xFFFFFF, et = pk >> 24;
      float lg = (et == 0 ? q0 : (et == 1 ? q1 : q2)) + QK[sn * 8 + 3 + et];
      l = lg >= 0.f ? lg : lg * SLOPE;
    }
    float mnew = fmaxf(m, wred_max(l));
    float ps = wred_sum((idx < end) ? __expf(l - mnew) : 0.f);
    s = s * __expf(m - mnew) + ps;
    m = mnew;
  }
  float inv = 1.f / (s + 1e-16f);
  float acc = 0.f;
  for (int c = beg; c < end; c += 64){
    int idx = c + lane;
    int off = 0; float wgt = 0.f;
    if (idx < end){
      int pk = csr[idx];
      int sn = pk & 0xFFFFFF, et = pk >> 24;
      float lg = (et == 0 ? q0 : (et == 1 ? q1 : q2)) + QK[sn * 8 + 3 + et];
      float l = lg >= 0.f ? lg : lg * SLOPE;
      wgt = __expf(l - m) * inv;
      off = sn * XRS + et * HID;
    }
    int cc = min(64, end - c);
    #pragma unroll 4
    for (int j = 0; j < cc; ++j){
      float wj = __uint_as_float(__builtin_amdgcn_readlane(__float_as_uint(wgt), j));
      int oj = __builtin_amdgcn_readlane(off, j);
      acc = fmaf(wj, bf2f(XRb[oj + lane]), acc);
    }
  }
  orow[lane] = acc + bv;
}

// ---- graph-level softmax aggregation ---------------------------------------
// grid (NG, 13); block 256 = 4 node-parallel waves x 64 features

__global__ __launch_bounds__(256) void agg_kernel(
    const float* __restrict__ nr, const int* __restrict__ gst,
    const float* __restrict__ tp, float* __restrict__ out){
  __shared__ float red[4][64];
  __shared__ float red2[4][64];
  int g = blockIdx.x;
  int lane = threadIdx.x & 63;
  int w = threadIdx.x >> 6;
  int f = blockIdx.y * 64 + lane;
  int s = gst[g], e = gst[g + 1];
  float tval = tp[0];
  float m = -INFINITY;
  for (int n = s + w; n < e; n += 4)
    m = fmaxf(m, nr[(size_t)n * NRS + f] * tval);
  red[w][lane] = m;
  __syncthreads();
  m = fmaxf(fmaxf(red[0][lane], red[1][lane]), fmaxf(red[2][lane], red[3][lane]));
  float ss = 0.f, acc = 0.f;
  for (int n = s + w; n < e; n += 4){
    float v = nr[(size_t)n * NRS + f];
    float ee = __expf(v * tval - m);
    ss += ee; acc = fmaf(v, ee, acc);
  }
  __syncthreads();
  red[w][lane] = ss; red2[w][lane] = acc;
  __syncthreads();
  if (w == 0){
    ss = red[0][lane] + red[1][lane] + red[2][lane] + red[3][lane];
    acc = red2[0][lane] + red2[1][lane] + red2[2][lane] + red2[3][lane];
    out[(size_t)g * NRS + f] = acc / (ss + 1e-16f);
  }
}

// ---- orchestration ----------------------------------------------------------

extern "C" void kernel_launch(void* const* d_in, const int* in_sizes, int n_in,
                              void* d_out, int out_size, void* d_ws, size_t ws_size,
                              hipStream_t stream){
  const float* x0   = (const float*)d_in[0];
  const int*   eidx = (const int*)d_in[1];
  const int*   etyp = (const int*)d_in[2];
  const int*   batch= (const int*)d_in[3];
  const float* Wf   = (const float*)d_in[4];
  const float* qf   = (const float*)d_in[5];
  const float* kf   = (const float*)d_in[6];
  const float* bf   = (const float*)d_in[7];
  const float* Ws   = (const float*)d_in[8];
  const float* qs   = (const float*)d_in[9];
  const float* ks   = (const float*)d_in[10];
  const float* bs   = (const float*)d_in[11];
  const float* tp   = (const float*)d_in[12];

  float* gout = (float*)d_out;                 // [256][832]
  float* nrep = gout + (size_t)NG * NRS;       // [50000][832]

  char* w = (char*)d_ws;
  unsigned short* XRb = (unsigned short*)w; w += (size_t)NN * XRS * 2;  // 19.2 MB
  float* QK   = (float*)w;  w += (size_t)NN * 8 * 4;          // 1.6 MB
  unsigned short* Wtg = (unsigned short*)w; w += (size_t)192 * IND * 2; // 49 KB
  int*   rowp = (int*)w;    w += (size_t)(NN + 2) * 4;
  int*   cnts = (int*)w;    w += (size_t)NN * 4;
  int*   gst  = (int*)w;    w += (size_t)(NG + 2) * 4;
  int*   bsum = (int*)w;    w += 64 * 4;
  int*   csr  = (int*)w;    w += (size_t)NE * 4;              // 6.4 MB

  const int* srcv = eidx;
  const int* dstv = eidx + NE;

  const int NB = (NN + 1023) / 1024;  // 49

  // CSR by dst + graph boundaries (once per call, reused by all 13 layers)
  hipMemsetAsync(cnts, 0, (size_t)NN * 4, stream);
  hist_kernel<<<(NE + 255) / 256, 256, 0, stream>>>(dstv, cnts);
  scan1_kernel<<<NB, 1024, 0, stream>>>(cnts, rowp, bsum);
  scan2_kernel<<<1, 64, 0, stream>>>(bsum, rowp, NB);
  scan3_kernel<<<NB, 1024, 0, stream>>>(rowp, bsum);
  hipMemsetAsync(cnts, 0, (size_t)NN * 4, stream);
  scatter_kernel<<<(NE + 255) / 256, 256, 0, stream>>>(srcv, dstv, etyp, rowp, cnts, csr);
  gstart_kernel<<<(NN + 256) / 256, 256, 0, stream>>>(batch, gst);

  for (int l = 0; l < 13; ++l){
    int K = (l == 0) ? IND : HID;
    const float* W  = (l == 0) ? Wf : (Ws + (size_t)(l - 1) * NREL * HID * HID);
    const float* q  = (l == 0) ? qf : (qs + (size_t)(l - 1) * HID);
    const float* kv = (l == 0) ? kf : (ks + (size_t)(l - 1) * HID);
    const float* b  = (l == 0) ? bf : (bs + (size_t)(l - 1) * HID);
    const float* x  = (l == 0) ? x0 : (nrep + (size_t)(l - 1) * HID);
    int ldx = (l == 0) ? IND : NRS;
    int tot = NREL * K * HID;
    wprep_kernel<<<(tot + 255) / 256, 256, 0, stream>>>(W, Wtg, K);
    mm_kernel<<<(NN + 63) / 64, 256, 0, stream>>>(x, ldx, K, Wtg, q, kv, XRb, QK);
    edge_kernel<<<(NN + 3) / 4, 256, 0, stream>>>(XRb, QK, csr, rowp, b, nrep + (size_t)l * HID);
  }
  dim3 ag(NG, 13);
  agg_kernel<<<ag, 256, 0, stream>>>(nrep, gst, tp, gout);
}

// Round 8
// 1016.258 us; speedup vs baseline: 1.9817x; 1.0366x over previous
//
#include <hip/hip_runtime.h>
#include <math.h>

#define NN 50000
#define NE 1600000
#define NG 256
#define IND 128
#define HID 64
#define NREL 3
#define SLOPE 0.2f
#define XRS 192        // XR row stride in elements (3 relations * 64)
#define NRS 832        // node_rep row stride = 13*64
#define WTP 136        // padded LDS stride for Wt (shorts): mult of 8 -> 16B aligned
#define W0SZ (192*128)           // layer-0 Wt table, shorts
#define WLSZ (192*64)            // layer-1..12 Wt table, shorts
#define WTOT (W0SZ + 12*WLSZ)    // 172032 shorts

typedef short bf16x8 __attribute__((ext_vector_type(8)));
typedef float f32x4 __attribute__((ext_vector_type(4)));

__device__ __forceinline__ float wred_max(float v){
  #pragma unroll
  for (int o = 32; o; o >>= 1) v = fmaxf(v, __shfl_xor(v, o));
  return v;
}
__device__ __forceinline__ float wred_sum(float v){
  #pragma unroll
  for (int o = 32; o; o >>= 1) v += __shfl_xor(v, o);
  return v;
}

__device__ __forceinline__ unsigned short f2bf(float f){
  unsigned int u = __float_as_uint(f);
  u = (u + 0x7FFFu + ((u >> 16) & 1u)) >> 16;   // RNE
  return (unsigned short)u;
}
__device__ __forceinline__ float bf2f(unsigned short h){
  return __uint_as_float(((unsigned int)h) << 16);
}

// ---- CSR build --------------------------------------------------------------

__global__ void hist_kernel(const int* __restrict__ dst, int* __restrict__ cnts){
  int e = blockIdx.x * blockDim.x + threadIdx.x;
  if (e < NE) atomicAdd(&cnts[dst[e]], 1);
}

// hierarchical exclusive scan of cnts[NN] -> rowp[NN+1]
__global__ void scan1_kernel(const int* __restrict__ cnts, int* __restrict__ rowp,
                             int* __restrict__ bsum){
  __shared__ int ws[16];
  int b = blockIdx.x, tid = threadIdx.x;
  int i = b * 1024 + tid;
  int lane = tid & 63, wid = tid >> 6;
  int v = (i < NN) ? cnts[i] : 0;
  int x = v;
  #pragma unroll
  for (int o = 1; o < 64; o <<= 1){ int t = __shfl_up(x, o); if (lane >= o) x += t; }
  if (lane == 63) ws[wid] = x;
  __syncthreads();
  if (tid < 16){
    int y = ws[tid];
    #pragma unroll
    for (int o = 1; o < 16; o <<= 1){ int t = __shfl_up(y, o); if (tid >= o) y += t; }
    ws[tid] = y;
  }
  __syncthreads();
  int off = (wid > 0) ? ws[wid - 1] : 0;
  x += off;                         // inclusive within block
  if (i < NN) rowp[i] = x - v;      // exclusive within block
  if (tid == 1023) bsum[b] = x;     // block total
}

__global__ void scan2_kernel(int* __restrict__ bsum, int* __restrict__ rowp, int nb){
  int tid = threadIdx.x;
  int v = (tid < nb) ? bsum[tid] : 0;
  int x = v;
  #pragma unroll
  for (int o = 1; o < 64; o <<= 1){ int t = __shfl_up(x, o); if (tid >= o) x += t; }
  if (tid < nb) bsum[tid] = x - v;  // exclusive block offsets
  if (tid == 63) rowp[NN] = x;      // grand total
}

__global__ void scan3_kernel(int* __restrict__ rowp, const int* __restrict__ bsum){
  int i = blockIdx.x * 1024 + threadIdx.x;
  if (i < NN) rowp[i] += bsum[blockIdx.x];
}

__global__ void scatter_kernel(const int* __restrict__ src, const int* __restrict__ dst,
                               const int* __restrict__ et, const int* __restrict__ rowp,
                               int* __restrict__ fill, int* __restrict__ csr){
  int e = blockIdx.x * blockDim.x + threadIdx.x;
  if (e >= NE) return;
  int d = dst[e];
  int pos = atomicAdd(&fill[d], 1);
  csr[rowp[d] + pos] = src[e] | (et[e] << 24);
}

// graph boundaries from sorted batch_index: gst[g] = first node with batch >= g
__global__ void gstart_kernel(const int* __restrict__ batch, int* __restrict__ gst){
  int n = blockIdx.x * blockDim.x + threadIdx.x;
  if (n > NN) return;
  int bc = (n < NN) ? batch[n] : NG;
  int bp = (n == 0) ? -1 : batch[n - 1];
  for (int g = bp + 1; g <= bc; ++g) gst[g] = n;
}

// ---- batched weight prep for ALL 13 layers ---------------------------------
// Wtg13 layout: layer0 [192][128] at 0; layer l>=1 [192][64] at W0SZ+(l-1)*WLSZ
// Wtg[col=r*64+h][k] = bf16(W_l[r][k][h])
__global__ void wprep13_kernel(const float* __restrict__ Wf, const float* __restrict__ Ws,
                               unsigned short* __restrict__ Wtg13){
  int i = blockIdx.x * blockDim.x + threadIdx.x;
  if (i >= WTOT) return;
  int j, K; size_t base; const float* W;
  if (i < W0SZ){ j = i; K = IND; base = 0; W = Wf; }
  else {
    int t = i - W0SZ;
    int l = t / WLSZ;                 // 0..11 -> layer l+1
    j = t - l * WLSZ; K = HID;
    base = W0SZ + (size_t)l * WLSZ;
    W = Ws + (size_t)l * WLSZ;
  }
  int h = j & 63;
  int k = (j >> 6) % K;
  int r = j / (K * HID);
  Wtg13[base + (size_t)((r << 6) + h) * K + k] = f2bf(W[j]);
}

// ---- MFMA GEMM: XRb[n][f] = bf16( sum_k x[n][k] * W[f][k] ), f = r*64+h ----
// A-op = W (M=16 features x K), B-op = x (K x N=16 rows).
// D layout: lane&15 = x-row, (lane>>4)*4+reg = feature  -> packed ushort4 C-store.
// Epilogue: QK[n][r] = xr_r . q ; QK[n][3+r] = xr_r . k  (xor-16/32 reduce)
__global__ __launch_bounds__(256) void mm_kernel(
    const float* __restrict__ x, int ldx, int K,
    const unsigned short* __restrict__ Wtg,
    const float* __restrict__ qv, const float* __restrict__ kv,
    unsigned short* __restrict__ XRb, float* __restrict__ QK){
  __shared__ unsigned short Wt[192 * WTP];
  int tid = threadIdx.x;
  int w = tid >> 6, lane = tid & 63;
  int lrow = lane & 15, kg = lane >> 4;      // x-row within wave tile, k-group
  int row0 = blockIdx.x * 64;
  int row = row0 + w * 16 + lrow;
  // stage Wtg -> LDS (16B copies, coalesced / conflict-free)
  int nb8 = 192 * (K >> 3);
  for (int i = tid; i < nb8; i += 256){
    int col = i / (K >> 3);
    int k8 = (i - col * (K >> 3)) << 3;
    *(bf16x8*)&Wt[col * WTP + k8] = *(const bf16x8*)&Wtg[(size_t)col * K + k8];
  }
  __syncthreads();

  f32x4 acc[12];
  #pragma unroll
  for (int t = 0; t < 12; ++t) acc[t] = (f32x4){0.f, 0.f, 0.f, 0.f};

  int ksteps = K >> 5;
  for (int ks = 0; ks < ksteps; ++ks){
    // x-fragment (B-op): 8 consecutive k as bf16
    bf16x8 xb;
    if (row < NN){
      const float* xp = x + (size_t)row * ldx + (ks << 5) + (kg << 3);
      float4 v0 = *(const float4*)xp;
      float4 v1 = *(const float4*)(xp + 4);
      xb[0] = (short)f2bf(v0.x); xb[1] = (short)f2bf(v0.y);
      xb[2] = (short)f2bf(v0.z); xb[3] = (short)f2bf(v0.w);
      xb[4] = (short)f2bf(v1.x); xb[5] = (short)f2bf(v1.y);
      xb[6] = (short)f2bf(v1.z); xb[7] = (short)f2bf(v1.w);
    } else {
      #pragma unroll
      for (int j = 0; j < 8; ++j) xb[j] = 0;
    }
    int kk = (ks << 5) + (kg << 3);
    #pragma unroll
    for (int t = 0; t < 12; ++t){
      bf16x8 wf = *(const bf16x8*)&Wt[(t * 16 + lrow) * WTP + kk];
      acc[t] = __builtin_amdgcn_mfma_f32_16x16x32_bf16(wf, xb, acc[t], 0, 0, 0);
    }
  }

  // C-store: lane holds features t*16 + kg*4 + j for x-row `row`
  if (row < NN){
    unsigned short* orow = XRb + (size_t)row * XRS;
    #pragma unroll
    for (int t = 0; t < 12; ++t){
      ushort4 o4;
      o4.x = f2bf(acc[t][0]); o4.y = f2bf(acc[t][1]);
      o4.z = f2bf(acc[t][2]); o4.w = f2bf(acc[t][3]);
      *(ushort4*)(orow + t * 16 + (kg << 2)) = o4;
    }
  }

  // epilogue: q/k dots. feature of (t,j) within relation: hcol = (t&3)*16 + kg*4 + j
  float pq[3] = {0,0,0}, pk[3] = {0,0,0};
  #pragma unroll
  for (int t = 0; t < 12; ++t){
    int r = t >> 2;
    int hbase = ((t & 3) << 4) + (kg << 2);
    #pragma unroll
    for (int j = 0; j < 4; ++j){
      float qc = qv[hbase + j], kc = kv[hbase + j];
      pq[r] = fmaf(acc[t][j], qc, pq[r]);
      pk[r] = fmaf(acc[t][j], kc, pk[r]);
    }
  }
  #pragma unroll
  for (int o = 16; o < 64; o <<= 1){
    #pragma unroll
    for (int r = 0; r < 3; ++r){
      pq[r] += __shfl_xor(pq[r], o);
      pk[r] += __shfl_xor(pk[r], o);
    }
  }
  if (kg == 0 && row < NN){
    #pragma unroll
    for (int r = 0; r < 3; ++r){
      QK[row * 8 + r] = pq[r];
      QK[row * 8 + 3 + r] = pk[r];
    }
  }
}

// ---- edge softmax + aggregation: one wave per dst node ----------------------
// Fast path (degree <= 128): logits in registers. Gather: broadcasts (w,o) for
// all 8 slots hoisted before the loop; 8 branch-free load slots so all loads
// issue back-to-back (invalid slots carry w=0, o=0 -> row-0 L1 hits).

__global__ __launch_bounds__(256) void edge_kernel(
    const unsigned short* __restrict__ XRb, const float* __restrict__ QK,
    const int* __restrict__ csr, const int* __restrict__ rowp,
    const float* __restrict__ bias, float* __restrict__ out){
  int wid = blockIdx.x * 4 + (threadIdx.x >> 6);
  int lane = threadIdx.x & 63;
  if (wid >= NN) return;
  int beg = rowp[wid], end = rowp[wid + 1];
  int cnt = end - beg;
  float* orow = out + (size_t)wid * NRS;
  int sub = lane & 7;        // feature chunk: features sub*8 .. sub*8+7
  int g   = lane >> 3;       // edge slot within group-of-8
  if (cnt == 0){
    if (lane < 8){
      float4 b0 = *(const float4*)(bias + sub * 8);
      float4 b1 = *(const float4*)(bias + sub * 8 + 4);
      *(float4*)(orow + sub * 8) = b0;
      *(float4*)(orow + sub * 8 + 4) = b1;
    }
    return;
  }
  float q0 = QK[wid * 8], q1 = QK[wid * 8 + 1], q2 = QK[wid * 8 + 2];

  if (cnt <= 128){
    // ---- logit phase: lane = edge (up to 2 regs) ----
    float l0 = -INFINITY, l1 = -INFINITY;
    int o0 = 0, o1 = 0;
    {
      int idx = beg + lane;
      if (idx < end){
        int pk = csr[idx];
        int sn = pk & 0xFFFFFF, et = pk >> 24;
        float lg = (et == 0 ? q0 : (et == 1 ? q1 : q2)) + QK[sn * 8 + 3 + et];
        l0 = lg >= 0.f ? lg : lg * SLOPE;
        o0 = sn * XRS + et * HID;
      }
      idx += 64;
      if (idx < end){
        int pk = csr[idx];
        int sn = pk & 0xFFFFFF, et = pk >> 24;
        float lg = (et == 0 ? q0 : (et == 1 ? q1 : q2)) + QK[sn * 8 + 3 + et];
        l1 = lg >= 0.f ? lg : lg * SLOPE;
        o1 = sn * XRS + et * HID;
      }
    }
    float m = wred_max(fmaxf(l0, l1));
    float e0 = __expf(l0 - m), e1 = __expf(l1 - m);  // exp(-inf)=0 -> invalid lanes get w=0
    float s = wred_sum(e0 + e1);
    float inv = 1.f / (s + 1e-16f);
    float w0 = e0 * inv, w1 = e1 * inv;

    const unsigned short* xp = XRb + sub * 8;
    float acc[8] = {};

    // hoist all slot broadcasts, then branch-free loads
    float wS[8]; int oS[8];
    #pragma unroll
    for (int e = 0; e < 8; ++e){
      int sl = (e << 3) + g;
      wS[e] = __shfl(w0, sl);
      oS[e] = __shfl(o0, sl);
    }
    int nIt = (min(cnt, 64) + 7) >> 3;
    #pragma unroll
    for (int e = 0; e < 8; ++e){
      uint4 d = *(const uint4*)(xp + oS[e]);   // w=0 slots read row 0 (L1 hot)
      float we = wS[e];
      acc[0] = fmaf(we, __uint_as_float(d.x << 16), acc[0]);
      acc[1] = fmaf(we, __uint_as_float(d.x & 0xFFFF0000u), acc[1]);
      acc[2] = fmaf(we, __uint_as_float(d.y << 16), acc[2]);
      acc[3] = fmaf(we, __uint_as_float(d.y & 0xFFFF0000u), acc[3]);
      acc[4] = fmaf(we, __uint_as_float(d.z << 16), acc[4]);
      acc[5] = fmaf(we, __uint_as_float(d.z & 0xFFFF0000u), acc[5]);
      acc[6] = fmaf(we, __uint_as_float(d.w << 16), acc[6]);
      acc[7] = fmaf(we, __uint_as_float(d.w & 0xFFFF0000u), acc[7]);
      if (e + 1 >= nIt) break;   // uniform early-out (keeps junk loads bounded)
    }
    if (cnt > 64){
      #pragma unroll
      for (int e = 0; e < 8; ++e){
        int sl = (e << 3) + g;
        wS[e] = __shfl(w1, sl);
        oS[e] = __shfl(o1, sl);
      }
      int nIt2 = (cnt - 64 + 7) >> 3;
      #pragma unroll
      for (int e = 0; e < 8; ++e){
        uint4 d = *(const uint4*)(xp + oS[e]);
        float we = wS[e];
        acc[0] = fmaf(we, __uint_as_float(d.x << 16), acc[0]);
        acc[1] = fmaf(we, __uint_as_float(d.x & 0xFFFF0000u), acc[1]);
        acc[2] = fmaf(we, __uint_as_float(d.y << 16), acc[2]);
        acc[3] = fmaf(we, __uint_as_float(d.y & 0xFFFF0000u), acc[3]);
        acc[4] = fmaf(we, __uint_as_float(d.z << 16), acc[4]);
        acc[5] = fmaf(we, __uint_as_float(d.z & 0xFFFF0000u), acc[5]);
        acc[6] = fmaf(we, __uint_as_float(d.w << 16), acc[6]);
        acc[7] = fmaf(we, __uint_as_float(d.w & 0xFFFF0000u), acc[7]);
        if (e + 1 >= nIt2) break;
      }
    }
    // reduce across the 8 edge-groups (lane bits 3..5)
    #pragma unroll
    for (int o = 8; o < 64; o <<= 1)
      #pragma unroll
      for (int j = 0; j < 8; ++j)
        acc[j] += __shfl_xor(acc[j], o);
    if (lane < 8){
      float4 b0 = *(const float4*)(bias + sub * 8);
      float4 b1 = *(const float4*)(bias + sub * 8 + 4);
      float4 r0, r1;
      r0.x = acc[0] + b0.x; r0.y = acc[1] + b0.y; r0.z = acc[2] + b0.z; r0.w = acc[3] + b0.w;
      r1.x = acc[4] + b1.x; r1.y = acc[5] + b1.y; r1.z = acc[6] + b1.z; r1.w = acc[7] + b1.w;
      *(float4*)(orow + sub * 8) = r0;
      *(float4*)(orow + sub * 8 + 4) = r1;
    }
    return;
  }

  // ---- fallback: arbitrary degree, online two-pass with recompute ----
  float bv = bias[lane];
  float m = -INFINITY, s = 0.f;
  for (int c = beg; c < end; c += 64){
    int idx = c + lane;
    float l = -INFINITY;
    if (idx < end){
      int pk = csr[idx];
      int sn = pk & 0xFFFFFF, et = pk >> 24;
      float lg = (et == 0 ? q0 : (et == 1 ? q1 : q2)) + QK[sn * 8 + 3 + et];
      l = lg >= 0.f ? lg : lg * SLOPE;
    }
    float mnew = fmaxf(m, wred_max(l));
    float ps = wred_sum((idx < end) ? __expf(l - mnew) : 0.f);
    s = s * __expf(m - mnew) + ps;
    m = mnew;
  }
  float inv = 1.f / (s + 1e-16f);
  float acc = 0.f;
  for (int c = beg; c < end; c += 64){
    int idx = c + lane;
    int off = 0; float wgt = 0.f;
    if (idx < end){
      int pk = csr[idx];
      int sn = pk & 0xFFFFFF, et = pk >> 24;
      float lg = (et == 0 ? q0 : (et == 1 ? q1 : q2)) + QK[sn * 8 + 3 + et];
      float l = lg >= 0.f ? lg : lg * SLOPE;
      wgt = __expf(l - m) * inv;
      off = sn * XRS + et * HID;
    }
    int cc = min(64, end - c);
    #pragma unroll 4
    for (int j = 0; j < cc; ++j){
      float wj = __uint_as_float(__builtin_amdgcn_readlane(__float_as_uint(wgt), j));
      int oj = __builtin_amdgcn_readlane(off, j);
      acc = fmaf(wj, bf2f(XRb[oj + lane]), acc);
    }
  }
  orow[lane] = acc + bv;
}

// ---- graph-level softmax aggregation: SINGLE PASS (online) ------------------
// grid (NG, 13); block 256 = 4 node-parallel waves x 64 features

__global__ __launch_bounds__(256) void agg_kernel(
    const float* __restrict__ nr, const int* __restrict__ gst,
    const float* __restrict__ tp, float* __restrict__ out){
  __shared__ float rm[4][64], rs[4][64], ra[4][64];
  int g = blockIdx.x;
  int lane = threadIdx.x & 63;
  int w = threadIdx.x >> 6;
  int f = blockIdx.y * 64 + lane;
  int s = gst[g], e = gst[g + 1];
  float tval = tp[0];
  float m = -INFINITY, ss = 0.f, ac = 0.f;
  for (int n = s + w; n < e; n += 4){
    float v = nr[(size_t)n * NRS + f];
    float vm = v * tval;
    float Mn = fmaxf(m, vm);
    float sc = __expf(m - Mn);        // first iter: exp(-inf)=0
    float ev = __expf(vm - Mn);
    ss = ss * sc + ev;
    ac = ac * sc + v * ev;
    m = Mn;
  }
  rm[w][lane] = m; rs[w][lane] = ss; ra[w][lane] = ac;
  __syncthreads();
  if (w == 0){
    float M = fmaxf(fmaxf(rm[0][lane], rm[1][lane]), fmaxf(rm[2][lane], rm[3][lane]));
    float S = 0.f, A = 0.f;
    #pragma unroll
    for (int i = 0; i < 4; ++i){
      float si = rs[i][lane];
      float sci = (si > 0.f) ? __expf(rm[i][lane] - M) : 0.f;
      S = fmaf(si, sci, S);
      A = fmaf(ra[i][lane], sci, A);
    }
    out[(size_t)g * NRS + f] = A / (S + 1e-16f);
  }
}

// ---- orchestration ----------------------------------------------------------

extern "C" void kernel_launch(void* const* d_in, const int* in_sizes, int n_in,
                              void* d_out, int out_size, void* d_ws, size_t ws_size,
                              hipStream_t stream){
  const float* x0   = (const float*)d_in[0];
  const int*   eidx = (const int*)d_in[1];
  const int*   etyp = (const int*)d_in[2];
  const int*   batch= (const int*)d_in[3];
  const float* Wf   = (const float*)d_in[4];
  const float* qf   = (const float*)d_in[5];
  const float* kf   = (const float*)d_in[6];
  const float* bf   = (const float*)d_in[7];
  const float* Ws   = (const float*)d_in[8];
  const float* qs   = (const float*)d_in[9];
  const float* ks   = (const float*)d_in[10];
  const float* bs   = (const float*)d_in[11];
  const float* tp   = (const float*)d_in[12];

  float* gout = (float*)d_out;                 // [256][832]
  float* nrep = gout + (size_t)NG * NRS;       // [50000][832]

  char* w = (char*)d_ws;
  unsigned short* XRb = (unsigned short*)w; w += (size_t)NN * XRS * 2;  // 19.2 MB
  float* QK   = (float*)w;  w += (size_t)NN * 8 * 4;          // 1.6 MB
  unsigned short* Wtg13 = (unsigned short*)w; w += (size_t)WTOT * 2;    // 344 KB
  int*   rowp = (int*)w;    w += (size_t)(NN + 2) * 4;
  int*   cnts = (int*)w;    w += (size_t)NN * 4;
  int*   gst  = (int*)w;    w += (size_t)(NG + 2) * 4;
  int*   bsum = (int*)w;    w += 64 * 4;
  int*   csr  = (int*)w;    w += (size_t)NE * 4;              // 6.4 MB

  const int* srcv = eidx;
  const int* dstv = eidx + NE;

  const int NB = (NN + 1023) / 1024;  // 49

  // CSR by dst + graph boundaries + all weight tables (once per call)
  hipMemsetAsync(cnts, 0, (size_t)NN * 4, stream);
  hist_kernel<<<(NE + 255) / 256, 256, 0, stream>>>(dstv, cnts);
  scan1_kernel<<<NB, 1024, 0, stream>>>(cnts, rowp, bsum);
  scan2_kernel<<<1, 64, 0, stream>>>(bsum, rowp, NB);
  scan3_kernel<<<NB, 1024, 0, stream>>>(rowp, bsum);
  hipMemsetAsync(cnts, 0, (size_t)NN * 4, stream);
  scatter_kernel<<<(NE + 255) / 256, 256, 0, stream>>>(srcv, dstv, etyp, rowp, cnts, csr);
  gstart_kernel<<<(NN + 256) / 256, 256, 0, stream>>>(batch, gst);
  wprep13_kernel<<<(WTOT + 255) / 256, 256, 0, stream>>>(Wf, Ws, Wtg13);

  for (int l = 0; l < 13; ++l){
    int K = (l == 0) ? IND : HID;
    const unsigned short* Wtg = Wtg13 + ((l == 0) ? 0 : (W0SZ + (size_t)(l - 1) * WLSZ));
    const float* q  = (l == 0) ? qf : (qs + (size_t)(l - 1) * HID);
    const float* kv = (l == 0) ? kf : (ks + (size_t)(l - 1) * HID);
    const float* b  = (l == 0) ? bf : (bs + (size_t)(l - 1) * HID);
    const float* x  = (l == 0) ? x0 : (nrep + (size_t)(l - 1) * HID);
    int ldx = (l == 0) ? IND : NRS;
    mm_kernel<<<(NN + 63) / 64, 256, 0, stream>>>(x, ldx, K, Wtg, q, kv, XRb, QK);
    edge_kernel<<<(NN + 3) / 4, 256, 0, stream>>>(XRb, QK, csr, rowp, b, nrep + (size_t)l * HID);
  }
  dim3 ag(NG, 13);
  agg_kernel<<<ag, 256, 0, stream>>>(nrep, gst, tp, gout);
}

// Round 9
// 903.489 us; speedup vs baseline: 2.2291x; 1.1248x over previous
//
#include <hip/hip_runtime.h>
#include <math.h>

#define NN 50000
#define NE 1600000
#define NG 256
#define IND 128
#define HID 64
#define NREL 3
#define SLOPE 0.2f
#define XRS 192        // XR row stride in elements (3 relations * 64)
#define NRS 832        // node_rep row stride = 13*64
#define WTP 136        // padded LDS stride for Wt (shorts): mult of 8 -> 16B aligned
#define W0SZ (192*128)           // layer-0 Wt table, shorts
#define WLSZ (192*64)            // layer-1..12 Wt table, shorts
#define WTOT (W0SZ + 12*WLSZ)    // 172032 shorts
#define NBKT 49                  // ceil(NN/1024)
#define ACHUNK 4096              // edges per pass-A block

typedef short bf16x8 __attribute__((ext_vector_type(8)));
typedef float f32x4 __attribute__((ext_vector_type(4)));

__device__ __forceinline__ float wred_max(float v){
  #pragma unroll
  for (int o = 32; o; o >>= 1) v = fmaxf(v, __shfl_xor(v, o));
  return v;
}
__device__ __forceinline__ float wred_sum(float v){
  #pragma unroll
  for (int o = 32; o; o >>= 1) v += __shfl_xor(v, o);
  return v;
}

__device__ __forceinline__ unsigned short f2bf(float f){
  unsigned int u = __float_as_uint(f);
  u = (u + 0x7FFFu + ((u >> 16) & 1u)) >> 16;   // RNE
  return (unsigned short)u;
}
__device__ __forceinline__ float bf2f(unsigned short h){
  return __uint_as_float(((unsigned int)h) << 16);
}

// ---- CSR build: two-level counting sort (L2-resident write windows) ---------

// pass A hist: coarse bucket counts via LDS histogram
__global__ __launch_bounds__(256) void bhistA_kernel(const int* __restrict__ dst,
                                                     int* __restrict__ bkt_cnt){
  __shared__ int h[64];
  int tid = threadIdx.x;
  if (tid < 64) h[tid] = 0;
  __syncthreads();
  int e0 = blockIdx.x * ACHUNK;
  int e1 = min(e0 + ACHUNK, NE);
  for (int i = e0 + tid; i < e1; i += 256)
    atomicAdd(&h[dst[i] >> 10], 1);
  __syncthreads();
  if (tid < 64 && h[tid] > 0) atomicAdd(&bkt_cnt[tid], h[tid]);
}

// scan 49 bucket counts -> bkt_base[0..49], init bkt_fill, set rowp[NN]
__global__ void bscan_kernel(const int* __restrict__ bkt_cnt, int* __restrict__ bkt_base,
                             int* __restrict__ bkt_fill, int* __restrict__ rowp){
  int tid = threadIdx.x;  // 64
  int v = (tid < NBKT) ? bkt_cnt[tid] : 0;
  int x = v;
  #pragma unroll
  for (int o = 1; o < 64; o <<= 1){ int t = __shfl_up(x, o); if (tid >= o) x += t; }
  int excl = x - v;
  if (tid <= NBKT){ bkt_base[tid] = excl; bkt_fill[tid] = excl; }
  if (tid == 0) rowp[NN] = NE;
}

// pass A scatter: chunk LDS hist -> one range reservation per bucket -> packed write
// packed record: dlocal(10b)<<18 | et(2b)<<16 | src(16b)
__global__ __launch_bounds__(256) void bscatA_kernel(
    const int* __restrict__ src, const int* __restrict__ dst, const int* __restrict__ et,
    int* __restrict__ bkt_fill, unsigned int* __restrict__ ebkt){
  __shared__ int h[64];
  __shared__ int bbase[64];
  int tid = threadIdx.x;
  if (tid < 64) h[tid] = 0;
  __syncthreads();
  int e0 = blockIdx.x * ACHUNK;
  int e1 = min(e0 + ACHUNK, NE);
  for (int i = e0 + tid; i < e1; i += 256)
    atomicAdd(&h[dst[i] >> 10], 1);
  __syncthreads();
  if (tid < 64) bbase[tid] = (h[tid] > 0) ? atomicAdd(&bkt_fill[tid], h[tid]) : 0;
  __syncthreads();
  if (tid < 64) h[tid] = 0;   // reuse as chunk-local fill
  __syncthreads();
  for (int i = e0 + tid; i < e1; i += 256){
    int d = dst[i];
    int b = d >> 10;
    int pos = atomicAdd(&h[b], 1);
    ebkt[bbase[b] + pos] =
        ((unsigned int)(d & 1023) << 18) | ((unsigned int)(et[i] & 3) << 16) | (unsigned int)src[i];
  }
}

// pass B: one block per bucket -> local hist, scan, rowp + contiguous csr scatter
__global__ __launch_bounds__(1024) void bsortB_kernel(
    const unsigned int* __restrict__ ebkt, const int* __restrict__ bkt_base,
    int* __restrict__ rowp, int* __restrict__ csr){
  __shared__ int cnt[1024];
  __shared__ int ws[16];
  int b = blockIdx.x, tid = threadIdx.x;
  int beg = bkt_base[b], end = bkt_base[b + 1];
  cnt[tid] = 0;
  __syncthreads();
  for (int i = beg + tid; i < end; i += 1024)
    atomicAdd(&cnt[(ebkt[i] >> 18) & 1023], 1);
  __syncthreads();
  int v = cnt[tid];
  int lane = tid & 63, wv = tid >> 6;
  int x = v;
  #pragma unroll
  for (int o = 1; o < 64; o <<= 1){ int t = __shfl_up(x, o); if (lane >= o) x += t; }
  if (lane == 63) ws[wv] = x;
  __syncthreads();
  if (tid < 16){
    int y = ws[tid];
    #pragma unroll
    for (int o = 1; o < 16; o <<= 1){ int t = __shfl_up(y, o); if (tid >= o) y += t; }
    ws[tid] = y;
  }
  __syncthreads();
  int excl = x + ((wv > 0) ? ws[wv - 1] : 0) - v;
  int node = b * 1024 + tid;
  if (node < NN) rowp[node] = beg + excl;
  cnt[tid] = excl;     // reuse as per-dst fill (relative to beg)
  __syncthreads();
  for (int i = beg + tid; i < end; i += 1024){
    unsigned int p = ebkt[i];
    int dl = (p >> 18) & 1023;
    int pos = atomicAdd(&cnt[dl], 1);
    csr[beg + pos] = (int)(p & 0x3FFFFu);   // src | et<<16
  }
}

// graph boundaries from sorted batch_index: gst[g] = first node with batch >= g
__global__ void gstart_kernel(const int* __restrict__ batch, int* __restrict__ gst){
  int n = blockIdx.x * blockDim.x + threadIdx.x;
  if (n > NN) return;
  int bc = (n < NN) ? batch[n] : NG;
  int bp = (n == 0) ? -1 : batch[n - 1];
  for (int g = bp + 1; g <= bc; ++g) gst[g] = n;
}

// ---- batched weight prep for ALL 13 layers ---------------------------------
__global__ void wprep13_kernel(const float* __restrict__ Wf, const float* __restrict__ Ws,
                               unsigned short* __restrict__ Wtg13){
  int i = blockIdx.x * blockDim.x + threadIdx.x;
  if (i >= WTOT) return;
  int j, K; size_t base; const float* W;
  if (i < W0SZ){ j = i; K = IND; base = 0; W = Wf; }
  else {
    int t = i - W0SZ;
    int l = t / WLSZ;                 // 0..11 -> layer l+1
    j = t - l * WLSZ; K = HID;
    base = W0SZ + (size_t)l * WLSZ;
    W = Ws + (size_t)l * WLSZ;
  }
  int h = j & 63;
  int k = (j >> 6) % K;
  int r = j / (K * HID);
  Wtg13[base + (size_t)((r << 6) + h) * K + k] = f2bf(W[j]);
}

// ---- MFMA GEMM: XRb[n][f] = bf16( sum_k x[n][k] * W[f][k] ), f = r*64+h ----
__global__ __launch_bounds__(256) void mm_kernel(
    const float* __restrict__ x, int ldx, int K,
    const unsigned short* __restrict__ Wtg,
    const float* __restrict__ qv, const float* __restrict__ kv,
    unsigned short* __restrict__ XRb, float* __restrict__ QK){
  __shared__ unsigned short Wt[192 * WTP];
  int tid = threadIdx.x;
  int w = tid >> 6, lane = tid & 63;
  int lrow = lane & 15, kg = lane >> 4;
  int row0 = blockIdx.x * 64;
  int row = row0 + w * 16 + lrow;
  int nb8 = 192 * (K >> 3);
  for (int i = tid; i < nb8; i += 256){
    int col = i / (K >> 3);
    int k8 = (i - col * (K >> 3)) << 3;
    *(bf16x8*)&Wt[col * WTP + k8] = *(const bf16x8*)&Wtg[(size_t)col * K + k8];
  }
  __syncthreads();

  f32x4 acc[12];
  #pragma unroll
  for (int t = 0; t < 12; ++t) acc[t] = (f32x4){0.f, 0.f, 0.f, 0.f};

  int ksteps = K >> 5;
  for (int ks = 0; ks < ksteps; ++ks){
    bf16x8 xb;
    if (row < NN){
      const float* xp = x + (size_t)row * ldx + (ks << 5) + (kg << 3);
      float4 v0 = *(const float4*)xp;
      float4 v1 = *(const float4*)(xp + 4);
      xb[0] = (short)f2bf(v0.x); xb[1] = (short)f2bf(v0.y);
      xb[2] = (short)f2bf(v0.z); xb[3] = (short)f2bf(v0.w);
      xb[4] = (short)f2bf(v1.x); xb[5] = (short)f2bf(v1.y);
      xb[6] = (short)f2bf(v1.z); xb[7] = (short)f2bf(v1.w);
    } else {
      #pragma unroll
      for (int j = 0; j < 8; ++j) xb[j] = 0;
    }
    int kk = (ks << 5) + (kg << 3);
    #pragma unroll
    for (int t = 0; t < 12; ++t){
      bf16x8 wf = *(const bf16x8*)&Wt[(t * 16 + lrow) * WTP + kk];
      acc[t] = __builtin_amdgcn_mfma_f32_16x16x32_bf16(wf, xb, acc[t], 0, 0, 0);
    }
  }

  if (row < NN){
    unsigned short* orow = XRb + (size_t)row * XRS;
    #pragma unroll
    for (int t = 0; t < 12; ++t){
      ushort4 o4;
      o4.x = f2bf(acc[t][0]); o4.y = f2bf(acc[t][1]);
      o4.z = f2bf(acc[t][2]); o4.w = f2bf(acc[t][3]);
      *(ushort4*)(orow + t * 16 + (kg << 2)) = o4;
    }
  }

  float pq[3] = {0,0,0}, pk[3] = {0,0,0};
  #pragma unroll
  for (int t = 0; t < 12; ++t){
    int r = t >> 2;
    int hbase = ((t & 3) << 4) + (kg << 2);
    #pragma unroll
    for (int j = 0; j < 4; ++j){
      float qc = qv[hbase + j], kc = kv[hbase + j];
      pq[r] = fmaf(acc[t][j], qc, pq[r]);
      pk[r] = fmaf(acc[t][j], kc, pk[r]);
    }
  }
  #pragma unroll
  for (int o = 16; o < 64; o <<= 1){
    #pragma unroll
    for (int r = 0; r < 3; ++r){
      pq[r] += __shfl_xor(pq[r], o);
      pk[r] += __shfl_xor(pk[r], o);
    }
  }
  if (kg == 0 && row < NN){
    #pragma unroll
    for (int r = 0; r < 3; ++r){
      QK[row * 8 + r] = pq[r];
      QK[row * 8 + 3 + r] = pk[r];
    }
  }
}

// ---- edge softmax + aggregation: one wave per dst node ----------------------
// csr entry: src(16b) | et(2b)<<16

__global__ __launch_bounds__(256) void edge_kernel(
    const unsigned short* __restrict__ XRb, const float* __restrict__ QK,
    const int* __restrict__ csr, const int* __restrict__ rowp,
    const float* __restrict__ bias, float* __restrict__ out){
  int wid = blockIdx.x * 4 + (threadIdx.x >> 6);
  int lane = threadIdx.x & 63;
  if (wid >= NN) return;
  int beg = rowp[wid], end = rowp[wid + 1];
  int cnt = end - beg;
  float* orow = out + (size_t)wid * NRS;
  int sub = lane & 7;
  int g   = lane >> 3;
  if (cnt == 0){
    if (lane < 8){
      float4 b0 = *(const float4*)(bias + sub * 8);
      float4 b1 = *(const float4*)(bias + sub * 8 + 4);
      *(float4*)(orow + sub * 8) = b0;
      *(float4*)(orow + sub * 8 + 4) = b1;
    }
    return;
  }
  float q0 = QK[wid * 8], q1 = QK[wid * 8 + 1], q2 = QK[wid * 8 + 2];

  if (cnt <= 128){
    float l0 = -INFINITY, l1 = -INFINITY;
    int o0 = 0, o1 = 0;
    {
      int idx = beg + lane;
      if (idx < end){
        int pk = csr[idx];
        int sn = pk & 0xFFFF, et = (pk >> 16) & 3;
        float lg = (et == 0 ? q0 : (et == 1 ? q1 : q2)) + QK[sn * 8 + 3 + et];
        l0 = lg >= 0.f ? lg : lg * SLOPE;
        o0 = sn * XRS + et * HID;
      }
      idx += 64;
      if (idx < end){
        int pk = csr[idx];
        int sn = pk & 0xFFFF, et = (pk >> 16) & 3;
        float lg = (et == 0 ? q0 : (et == 1 ? q1 : q2)) + QK[sn * 8 + 3 + et];
        l1 = lg >= 0.f ? lg : lg * SLOPE;
        o1 = sn * XRS + et * HID;
      }
    }
    float m = wred_max(fmaxf(l0, l1));
    float e0 = __expf(l0 - m), e1 = __expf(l1 - m);
    float s = wred_sum(e0 + e1);
    float inv = 1.f / (s + 1e-16f);
    float w0 = e0 * inv, w1 = e1 * inv;

    const unsigned short* xp = XRb + sub * 8;
    float acc[8] = {};

    float wS[8]; int oS[8];
    #pragma unroll
    for (int e = 0; e < 8; ++e){
      int sl = (e << 3) + g;
      wS[e] = __shfl(w0, sl);
      oS[e] = __shfl(o0, sl);
    }
    int nIt = (min(cnt, 64) + 7) >> 3;
    #pragma unroll
    for (int e = 0; e < 8; ++e){
      uint4 d = *(const uint4*)(xp + oS[e]);
      float we = wS[e];
      acc[0] = fmaf(we, __uint_as_float(d.x << 16), acc[0]);
      acc[1] = fmaf(we, __uint_as_float(d.x & 0xFFFF0000u), acc[1]);
      acc[2] = fmaf(we, __uint_as_float(d.y << 16), acc[2]);
      acc[3] = fmaf(we, __uint_as_float(d.y & 0xFFFF0000u), acc[3]);
      acc[4] = fmaf(we, __uint_as_float(d.z << 16), acc[4]);
      acc[5] = fmaf(we, __uint_as_float(d.z & 0xFFFF0000u), acc[5]);
      acc[6] = fmaf(we, __uint_as_float(d.w << 16), acc[6]);
      acc[7] = fmaf(we, __uint_as_float(d.w & 0xFFFF0000u), acc[7]);
      if (e + 1 >= nIt) break;
    }
    if (cnt > 64){
      #pragma unroll
      for (int e = 0; e < 8; ++e){
        int sl = (e << 3) + g;
        wS[e] = __shfl(w1, sl);
        oS[e] = __shfl(o1, sl);
      }
      int nIt2 = (cnt - 64 + 7) >> 3;
      #pragma unroll
      for (int e = 0; e < 8; ++e){
        uint4 d = *(const uint4*)(xp + oS[e]);
        float we = wS[e];
        acc[0] = fmaf(we, __uint_as_float(d.x << 16), acc[0]);
        acc[1] = fmaf(we, __uint_as_float(d.x & 0xFFFF0000u), acc[1]);
        acc[2] = fmaf(we, __uint_as_float(d.y << 16), acc[2]);
        acc[3] = fmaf(we, __uint_as_float(d.y & 0xFFFF0000u), acc[3]);
        acc[4] = fmaf(we, __uint_as_float(d.z << 16), acc[4]);
        acc[5] = fmaf(we, __uint_as_float(d.z & 0xFFFF0000u), acc[5]);
        acc[6] = fmaf(we, __uint_as_float(d.w << 16), acc[6]);
        acc[7] = fmaf(we, __uint_as_float(d.w & 0xFFFF0000u), acc[7]);
        if (e + 1 >= nIt2) break;
      }
    }
    #pragma unroll
    for (int o = 8; o < 64; o <<= 1)
      #pragma unroll
      for (int j = 0; j < 8; ++j)
        acc[j] += __shfl_xor(acc[j], o);
    if (lane < 8){
      float4 b0 = *(const float4*)(bias + sub * 8);
      float4 b1 = *(const float4*)(bias + sub * 8 + 4);
      float4 r0, r1;
      r0.x = acc[0] + b0.x; r0.y = acc[1] + b0.y; r0.z = acc[2] + b0.z; r0.w = acc[3] + b0.w;
      r1.x = acc[4] + b1.x; r1.y = acc[5] + b1.y; r1.z = acc[6] + b1.z; r1.w = acc[7] + b1.w;
      *(float4*)(orow + sub * 8) = r0;
      *(float4*)(orow + sub * 8 + 4) = r1;
    }
    return;
  }

  // ---- fallback: arbitrary degree, online two-pass with recompute ----
  float bv = bias[lane];
  float m = -INFINITY, s = 0.f;
  for (int c = beg; c < end; c += 64){
    int idx = c + lane;
    float l = -INFINITY;
    if (idx < end){
      int pk = csr[idx];
      int sn = pk & 0xFFFF, et = (pk >> 16) & 3;
      float lg = (et == 0 ? q0 : (et == 1 ? q1 : q2)) + QK[sn * 8 + 3 + et];
      l = lg >= 0.f ? lg : lg * SLOPE;
    }
    float mnew = fmaxf(m, wred_max(l));
    float ps = wred_sum((idx < end) ? __expf(l - mnew) : 0.f);
    s = s * __expf(m - mnew) + ps;
    m = mnew;
  }
  float inv = 1.f / (s + 1e-16f);
  float acc = 0.f;
  for (int c = beg; c < end; c += 64){
    int idx = c + lane;
    int off = 0; float wgt = 0.f;
    if (idx < end){
      int pk = csr[idx];
      int sn = pk & 0xFFFF, et = (pk >> 16) & 3;
      float lg = (et == 0 ? q0 : (et == 1 ? q1 : q2)) + QK[sn * 8 + 3 + et];
      float l = lg >= 0.f ? lg : lg * SLOPE;
      wgt = __expf(l - m) * inv;
      off = sn * XRS + et * HID;
    }
    int cc = min(64, end - c);
    #pragma unroll 4
    for (int j = 0; j < cc; ++j){
      float wj = __uint_as_float(__builtin_amdgcn_readlane(__float_as_uint(wgt), j));
      int oj = __builtin_amdgcn_readlane(off, j);
      acc = fmaf(wj, bf2f(XRb[oj + lane]), acc);
    }
  }
  orow[lane] = acc + bv;
}

// ---- graph-level softmax aggregation: SINGLE PASS (online) ------------------
__global__ __launch_bounds__(256) void agg_kernel(
    const float* __restrict__ nr, const int* __restrict__ gst,
    const float* __restrict__ tp, float* __restrict__ out){
  __shared__ float rm[4][64], rs[4][64], ra[4][64];
  int g = blockIdx.x;
  int lane = threadIdx.x & 63;
  int w = threadIdx.x >> 6;
  int f = blockIdx.y * 64 + lane;
  int s = gst[g], e = gst[g + 1];
  float tval = tp[0];
  float m = -INFINITY, ss = 0.f, ac = 0.f;
  for (int n = s + w; n < e; n += 4){
    float v = nr[(size_t)n * NRS + f];
    float vm = v * tval;
    float Mn = fmaxf(m, vm);
    float sc = __expf(m - Mn);
    float ev = __expf(vm - Mn);
    ss = ss * sc + ev;
    ac = ac * sc + v * ev;
    m = Mn;
  }
  rm[w][lane] = m; rs[w][lane] = ss; ra[w][lane] = ac;
  __syncthreads();
  if (w == 0){
    float M = fmaxf(fmaxf(rm[0][lane], rm[1][lane]), fmaxf(rm[2][lane], rm[3][lane]));
    float S = 0.f, A = 0.f;
    #pragma unroll
    for (int i = 0; i < 4; ++i){
      float si = rs[i][lane];
      float sci = (si > 0.f) ? __expf(rm[i][lane] - M) : 0.f;
      S = fmaf(si, sci, S);
      A = fmaf(ra[i][lane], sci, A);
    }
    out[(size_t)g * NRS + f] = A / (S + 1e-16f);
  }
}

// ---- orchestration ----------------------------------------------------------

extern "C" void kernel_launch(void* const* d_in, const int* in_sizes, int n_in,
                              void* d_out, int out_size, void* d_ws, size_t ws_size,
                              hipStream_t stream){
  const float* x0   = (const float*)d_in[0];
  const int*   eidx = (const int*)d_in[1];
  const int*   etyp = (const int*)d_in[2];
  const int*   batch= (const int*)d_in[3];
  const float* Wf   = (const float*)d_in[4];
  const float* qf   = (const float*)d_in[5];
  const float* kf   = (const float*)d_in[6];
  const float* bf   = (const float*)d_in[7];
  const float* Ws   = (const float*)d_in[8];
  const float* qs   = (const float*)d_in[9];
  const float* ks   = (const float*)d_in[10];
  const float* bs   = (const float*)d_in[11];
  const float* tp   = (const float*)d_in[12];

  float* gout = (float*)d_out;                 // [256][832]
  float* nrep = gout + (size_t)NG * NRS;       // [50000][832]

  char* w = (char*)d_ws;
  unsigned short* XRb = (unsigned short*)w; w += (size_t)NN * XRS * 2;  // 19.2 MB
  float* QK   = (float*)w;  w += (size_t)NN * 8 * 4;          // 1.6 MB
  unsigned short* Wtg13 = (unsigned short*)w; w += (size_t)WTOT * 2;    // 344 KB
  int*   rowp = (int*)w;    w += (size_t)(NN + 2) * 4;
  int*   gst  = (int*)w;    w += (size_t)(NG + 2) * 4;
  int*   bkt_cnt  = (int*)w; w += 64 * 4;
  int*   bkt_base = (int*)w; w += 64 * 4;
  int*   bkt_fill = (int*)w; w += 64 * 4;
  unsigned int* ebkt = (unsigned int*)w; w += (size_t)NE * 4;  // 6.4 MB
  int*   csr  = (int*)w;    w += (size_t)NE * 4;              // 6.4 MB

  const int* srcv = eidx;
  const int* dstv = eidx + NE;

  const int NAB = (NE + ACHUNK - 1) / ACHUNK;   // 391

  // CSR build (two-level counting sort) + graph boundaries + weight tables
  hipMemsetAsync(bkt_cnt, 0, 64 * 4, stream);
  bhistA_kernel<<<NAB, 256, 0, stream>>>(dstv, bkt_cnt);
  bscan_kernel<<<1, 64, 0, stream>>>(bkt_cnt, bkt_base, bkt_fill, rowp);
  bscatA_kernel<<<NAB, 256, 0, stream>>>(srcv, dstv, etyp, bkt_fill, ebkt);
  bsortB_kernel<<<NBKT, 1024, 0, stream>>>(ebkt, bkt_base, rowp, csr);
  gstart_kernel<<<(NN + 256) / 256, 256, 0, stream>>>(batch, gst);
  wprep13_kernel<<<(WTOT + 255) / 256, 256, 0, stream>>>(Wf, Ws, Wtg13);

  for (int l = 0; l < 13; ++l){
    int K = (l == 0) ? IND : HID;
    const unsigned short* Wtg = Wtg13 + ((l == 0) ? 0 : (W0SZ + (size_t)(l - 1) * WLSZ));
    const float* q  = (l == 0) ? qf : (qs + (size_t)(l - 1) * HID);
    const float* kv = (l == 0) ? kf : (ks + (size_t)(l - 1) * HID);
    const float* b  = (l == 0) ? bf : (bs + (size_t)(l - 1) * HID);
    const float* x  = (l == 0) ? x0 : (nrep + (size_t)(l - 1) * HID);
    int ldx = (l == 0) ? IND : NRS;
    mm_kernel<<<(NN + 63) / 64, 256, 0, stream>>>(x, ldx, K, Wtg, q, kv, XRb, QK);
    edge_kernel<<<(NN + 3) / 4, 256, 0, stream>>>(XRb, QK, csr, rowp, b, nrep + (size_t)l * HID);
  }
  dim3 ag(NG, 13);
  agg_kernel<<<ag, 256, 0, stream>>>(nrep, gst, tp, gout);
}